// Round 1
// baseline (485.400 us; speedup 1.0000x reference)
//
#include <hip/hip_runtime.h>
#include <math.h>

#define NN 50000
#define NE 800000
#define ETOT (NE + NN)
#define LEAKY 0.2f
#define BN_EPS 1e-5f

__global__ void k_zero(int* __restrict__ p, int n) {
    int i = blockIdx.x * blockDim.x + threadIdx.x;
    if (i < n) p[i] = 0;
}

__global__ void k_count(const int* __restrict__ ei, int* __restrict__ counts) {
    int e = blockIdx.x * blockDim.x + threadIdx.x;
    if (e >= ETOT) return;
    int dst = (e < NE) ? ei[NE + e] : (e - NE);
    atomicAdd(&counts[dst], 1);
}

__global__ __launch_bounds__(1024) void k_scan(const int* __restrict__ counts,
                                               int* __restrict__ offsets,
                                               int* __restrict__ cursor) {
    __shared__ int sums[1024];
    const int C = (NN + 1023) / 1024;  // 49
    int t = threadIdx.x;
    int begin = t * C, end = min(begin + C, NN);
    int s = 0;
    for (int i = begin; i < end; ++i) s += counts[i];
    sums[t] = s;
    __syncthreads();
    for (int off = 1; off < 1024; off <<= 1) {
        int v = 0;
        if (t >= off) v = sums[t - off];
        __syncthreads();
        if (t >= off) sums[t] += v;
        __syncthreads();
    }
    int run = (t == 0) ? 0 : sums[t - 1];
    for (int i = begin; i < end; ++i) {
        offsets[i] = run;
        cursor[i] = run;
        run += counts[i];
    }
    if (t == 1023) offsets[NN] = sums[1023];
}

__global__ void k_scatter(const int* __restrict__ ei, int* __restrict__ cursor,
                          int* __restrict__ sorted_src) {
    int e = blockIdx.x * blockDim.x + threadIdx.x;
    if (e >= ETOT) return;
    int src, dst;
    if (e < NE) { src = ei[e]; dst = ei[NE + e]; }
    else        { src = e - NE; dst = e - NE; }
    int pos = atomicAdd(&cursor[dst], 1);
    sorted_src[pos] = src;
}

// h1 = x @ W1   (x: [NN,128], W1: [128,128])
__global__ __launch_bounds__(256) void k_gemm1(const float* __restrict__ x,
                                               const float* __restrict__ W,
                                               float* __restrict__ h1) {
    __shared__ float Wl[128 * 128];   // 64 KB
    __shared__ float xs[128 * 68];    // transposed x tile, padded (34.8 KB)
    int t = threadIdx.x;
    int row0 = blockIdx.x * 64;
    // stage W (row-major, coalesced float4)
    #pragma unroll
    for (int i = 0; i < 16; ++i) {
        int idx = t * 4 + i * 1024;
        *(float4*)&Wl[idx] = *(const float4*)&W[idx];
    }
    // stage x transposed: xs[k][r]
    #pragma unroll
    for (int i = 0; i < 8; ++i) {
        int flat = t * 4 + i * 1024;
        int r = flat >> 7, k = flat & 127;
        float4 v = make_float4(0.f, 0.f, 0.f, 0.f);
        if (row0 + r < NN) v = *(const float4*)&x[(size_t)(row0 + r) * 128 + k];
        xs[(k + 0) * 68 + r] = v.x;
        xs[(k + 1) * 68 + r] = v.y;
        xs[(k + 2) * 68 + r] = v.z;
        xs[(k + 3) * 68 + r] = v.w;
    }
    __syncthreads();
    int tr = t >> 4, tc = t & 15;
    int c0 = tc * 8;
    float acc[4][8];
    #pragma unroll
    for (int i = 0; i < 4; ++i)
        #pragma unroll
        for (int j = 0; j < 8; ++j) acc[i][j] = 0.f;
    #pragma unroll 8
    for (int k = 0; k < 128; ++k) {
        float4 a  = *(const float4*)&xs[k * 68 + tr * 4];
        float4 b0 = *(const float4*)&Wl[k * 128 + c0];
        float4 b1 = *(const float4*)&Wl[k * 128 + c0 + 4];
        float av[4] = {a.x, a.y, a.z, a.w};
        float bv[8] = {b0.x, b0.y, b0.z, b0.w, b1.x, b1.y, b1.z, b1.w};
        #pragma unroll
        for (int i = 0; i < 4; ++i)
            #pragma unroll
            for (int j = 0; j < 8; ++j) acc[i][j] = fmaf(av[i], bv[j], acc[i][j]);
    }
    #pragma unroll
    for (int i = 0; i < 4; ++i) {
        int r = row0 + tr * 4 + i;
        if (r < NN) {
            float4 o0 = make_float4(acc[i][0], acc[i][1], acc[i][2], acc[i][3]);
            float4 o1 = make_float4(acc[i][4], acc[i][5], acc[i][6], acc[i][7]);
            *(float4*)&h1[(size_t)r * 128 + c0] = o0;
            *(float4*)&h1[(size_t)r * 128 + c0 + 4] = o1;
        }
    }
}

// per-node attention coefficients for layer 1: es/ed [NN,4]
__global__ void k_att1(const float* __restrict__ h1, const float* __restrict__ a_src,
                       const float* __restrict__ a_dst, float* __restrict__ es,
                       float* __restrict__ ed) {
    int t = threadIdx.x;
    int node = blockIdx.x * 8 + (t >> 5);
    if (node >= NN) return;
    int j = t & 31;
    int head = j >> 3;
    int cb = (j * 4) & 31;
    float4 v = *(const float4*)&h1[(size_t)node * 128 + j * 4];
    float ps = v.x * a_src[head * 32 + cb]     + v.y * a_src[head * 32 + cb + 1]
             + v.z * a_src[head * 32 + cb + 2] + v.w * a_src[head * 32 + cb + 3];
    float pd = v.x * a_dst[head * 32 + cb]     + v.y * a_dst[head * 32 + cb + 1]
             + v.z * a_dst[head * 32 + cb + 2] + v.w * a_dst[head * 32 + cb + 3];
    #pragma unroll
    for (int off = 1; off < 8; off <<= 1) {
        ps += __shfl_xor(ps, off);
        pd += __shfl_xor(pd, off);
    }
    if ((j & 7) == 0) {
        es[node * 4 + head] = ps;
        ed[node * 4 + head] = pd;
    }
}

// layer-1 aggregation (online softmax) + bias + BN + ELU, wave per node
__global__ __launch_bounds__(256) void k_agg1(
        const float* __restrict__ h1, const float* __restrict__ es,
        const float* __restrict__ ed, const int* __restrict__ offsets,
        const int* __restrict__ sorted_src, const float* __restrict__ b1,
        const float* __restrict__ gamma, const float* __restrict__ beta,
        const float* __restrict__ mean, const float* __restrict__ var,
        float* __restrict__ hbn) {
    int node = blockIdx.x * 4 + (threadIdx.x >> 6);
    if (node >= NN) return;
    int l = threadIdx.x & 63;
    int head = l >> 4;
    int p0 = offsets[node], p1 = offsets[node + 1];
    float edv = ed[node * 4 + head];
    float m = -1e30f, s = 0.f, acc0 = 0.f, acc1 = 0.f;
    for (int p = p0; p < p1; ++p) {
        int srcn = sorted_src[p];
        float e = es[srcn * 4 + head] + edv;
        e = e > 0.f ? e : LEAKY * e;
        float mn = fmaxf(m, e);
        float scale = __expf(m - mn);
        float w = __expf(e - mn);
        float2 hv = *(const float2*)&h1[(size_t)srcn * 128 + 2 * l];
        s = s * scale + w;
        acc0 = acc0 * scale + w * hv.x;
        acc1 = acc1 * scale + w * hv.y;
        m = mn;
    }
    float inv = 1.f / s;
    int i0 = 2 * l, i1 = 2 * l + 1;
    float o0 = acc0 * inv + b1[i0];
    float o1 = acc1 * inv + b1[i1];
    o0 = (o0 - mean[i0]) * rsqrtf(var[i0] + BN_EPS) * gamma[i0] + beta[i0];
    o1 = (o1 - mean[i1]) * rsqrtf(var[i1] + BN_EPS) * gamma[i1] + beta[i1];
    o0 = o0 > 0.f ? o0 : __expf(o0) - 1.f;
    o1 = o1 > 0.f ? o1 : __expf(o1) - 1.f;
    *(float2*)&hbn[(size_t)node * 128 + 2 * l] = make_float2(o0, o1);
}

// h2 = hbn @ W2   (hbn: [NN,128], W2: [128,40])
__global__ __launch_bounds__(256) void k_gemm2(const float* __restrict__ hbn,
                                               const float* __restrict__ W,
                                               float* __restrict__ h2) {
    __shared__ float Wl[128 * 40];     // 20.5 KB
    __shared__ float xs[128 * 132];    // 67.6 KB
    int t = threadIdx.x;
    int row0 = blockIdx.x * 128;
    for (int i = t; i < 128 * 40 / 4; i += 256)
        *(float4*)&Wl[i * 4] = *(const float4*)&W[i * 4];
    #pragma unroll
    for (int i = 0; i < 16; ++i) {
        int flat = t * 4 + i * 1024;
        int r = flat >> 7, k = flat & 127;
        float4 v = make_float4(0.f, 0.f, 0.f, 0.f);
        if (row0 + r < NN) v = *(const float4*)&hbn[(size_t)(row0 + r) * 128 + k];
        xs[(k + 0) * 132 + r] = v.x;
        xs[(k + 1) * 132 + r] = v.y;
        xs[(k + 2) * 132 + r] = v.z;
        xs[(k + 3) * 132 + r] = v.w;
    }
    __syncthreads();
    int tr = t >> 3, tc = t & 7;   // 32 x 8
    int r0 = tr * 4, c0 = tc * 5;
    float acc[4][5];
    #pragma unroll
    for (int i = 0; i < 4; ++i)
        #pragma unroll
        for (int j = 0; j < 5; ++j) acc[i][j] = 0.f;
    #pragma unroll 4
    for (int k = 0; k < 128; ++k) {
        float4 a = *(const float4*)&xs[k * 132 + r0];
        float av[4] = {a.x, a.y, a.z, a.w};
        float bv[5];
        #pragma unroll
        for (int j = 0; j < 5; ++j) bv[j] = Wl[k * 40 + c0 + j];
        #pragma unroll
        for (int i = 0; i < 4; ++i)
            #pragma unroll
            for (int j = 0; j < 5; ++j) acc[i][j] = fmaf(av[i], bv[j], acc[i][j]);
    }
    #pragma unroll
    for (int i = 0; i < 4; ++i) {
        int r = row0 + r0 + i;
        if (r < NN) {
            #pragma unroll
            for (int j = 0; j < 5; ++j) h2[(size_t)r * 40 + c0 + j] = acc[i][j];
        }
    }
}

// per-node attention coefficients layer 2
__global__ void k_att2(const float* __restrict__ h2, const float* __restrict__ a_src,
                       const float* __restrict__ a_dst, float* __restrict__ es,
                       float* __restrict__ ed) {
    int node = blockIdx.x * 4 + (threadIdx.x >> 6);
    if (node >= NN) return;
    int l = threadIdx.x & 63;
    float ps = 0.f, pd = 0.f;
    if (l < 40) {
        float v = h2[(size_t)node * 40 + l];
        ps = v * a_src[l];
        pd = v * a_dst[l];
    }
    #pragma unroll
    for (int off = 1; off < 64; off <<= 1) {
        ps += __shfl_xor(ps, off);
        pd += __shfl_xor(pd, off);
    }
    if (l == 0) { es[node] = ps; ed[node] = pd; }
}

// layer-2 aggregation + bias + log_softmax, wave per node
__global__ __launch_bounds__(256) void k_agg2(
        const float* __restrict__ h2, const float* __restrict__ es,
        const float* __restrict__ ed, const int* __restrict__ offsets,
        const int* __restrict__ sorted_src, const float* __restrict__ b2,
        float* __restrict__ out) {
    int node = blockIdx.x * 4 + (threadIdx.x >> 6);
    if (node >= NN) return;
    int l = threadIdx.x & 63;
    int p0 = offsets[node], p1 = offsets[node + 1];
    float edv = ed[node];
    float m = -1e30f, s = 0.f, acc = 0.f;
    for (int p = p0; p < p1; ++p) {
        int srcn = sorted_src[p];
        float e = es[srcn] + edv;
        e = e > 0.f ? e : LEAKY * e;
        float mn = fmaxf(m, e);
        float scale = __expf(m - mn);
        float w = __expf(e - mn);
        float hv = (l < 40) ? h2[(size_t)srcn * 40 + l] : 0.f;
        s = s * scale + w;
        acc = acc * scale + w * hv;
        m = mn;
    }
    float v = acc / s + ((l < 40) ? b2[l] : 0.f);
    float mv = (l < 40) ? v : -1e30f;
    #pragma unroll
    for (int off = 1; off < 64; off <<= 1) mv = fmaxf(mv, __shfl_xor(mv, off));
    float ex = (l < 40) ? __expf(v - mv) : 0.f;
    #pragma unroll
    for (int off = 1; off < 64; off <<= 1) ex += __shfl_xor(ex, off);
    if (l < 40) out[(size_t)node * 40 + l] = v - mv - __logf(ex);
}

extern "C" void kernel_launch(void* const* d_in, const int* in_sizes, int n_in,
                              void* d_out, int out_size, void* d_ws, size_t ws_size,
                              hipStream_t stream) {
    const float* x   = (const float*)d_in[0];
    const int*   ei  = (const int*)d_in[1];
    const float* W1  = (const float*)d_in[2];
    const float* a1s = (const float*)d_in[3];
    const float* a1d = (const float*)d_in[4];
    const float* b1  = (const float*)d_in[5];
    const float* bng = (const float*)d_in[6];
    const float* bnb = (const float*)d_in[7];
    const float* bnm = (const float*)d_in[8];
    const float* bnv = (const float*)d_in[9];
    const float* W2  = (const float*)d_in[10];
    const float* a2s = (const float*)d_in[11];
    const float* a2d = (const float*)d_in[12];
    const float* b2  = (const float*)d_in[13];
    float* out = (float*)d_out;

    char* ws = (char*)d_ws;
    size_t off = 0;
    auto alloc = [&](size_t bytes) -> void* {
        void* p = ws + off;
        off = (off + bytes + 255) & ~(size_t)255;
        return p;
    };
    int*   counts  = (int*)alloc((size_t)NN * 4);
    int*   cursor  = (int*)alloc((size_t)NN * 4);
    int*   offsets = (int*)alloc((size_t)(NN + 1) * 4);
    int*   ssrc    = (int*)alloc((size_t)ETOT * 4);
    float* h1      = (float*)alloc((size_t)NN * 128 * 4);
    float* es1     = (float*)alloc((size_t)NN * 4 * 4);
    float* ed1     = (float*)alloc((size_t)NN * 4 * 4);
    float* hbn     = (float*)alloc((size_t)NN * 128 * 4);
    float* h2      = (float*)alloc((size_t)NN * 40 * 4);
    float* es2     = (float*)alloc((size_t)NN * 4);
    float* ed2     = (float*)alloc((size_t)NN * 4);

    k_zero<<<(NN + 255) / 256, 256, 0, stream>>>(counts, NN);
    k_count<<<(ETOT + 255) / 256, 256, 0, stream>>>(ei, counts);
    k_scan<<<1, 1024, 0, stream>>>(counts, offsets, cursor);
    k_scatter<<<(ETOT + 255) / 256, 256, 0, stream>>>(ei, cursor, ssrc);
    k_gemm1<<<(NN + 63) / 64, 256, 0, stream>>>(x, W1, h1);
    k_att1<<<(NN + 7) / 8, 256, 0, stream>>>(h1, a1s, a1d, es1, ed1);
    k_agg1<<<(NN + 3) / 4, 256, 0, stream>>>(h1, es1, ed1, offsets, ssrc,
                                             b1, bng, bnb, bnm, bnv, hbn);
    k_gemm2<<<(NN + 127) / 128, 256, 0, stream>>>(hbn, W2, h2);
    k_att2<<<(NN + 3) / 4, 256, 0, stream>>>(h2, a2s, a2d, es2, ed2);
    k_agg2<<<(NN + 3) / 4, 256, 0, stream>>>(h2, es2, ed2, offsets, ssrc, b2, out);
}

// Round 2
// 385.352 us; speedup vs baseline: 1.2596x; 1.2596x over previous
//
#include <hip/hip_runtime.h>
#include <math.h>

#define NN 50000
#define NE 800000
#define ETOT (NE + NN)
#define LEAKY 0.2f
#define BN_EPS 1e-5f

#define SCAN_B 256
#define SCAN_NBLK ((NN + SCAN_B - 1) / SCAN_B)   // 196

__global__ void k_zero(int* __restrict__ p, int n) {
    int i = blockIdx.x * blockDim.x + threadIdx.x;
    if (i < n) p[i] = 0;
}

__global__ void k_count(const int* __restrict__ ei, int* __restrict__ counts) {
    int e = blockIdx.x * blockDim.x + threadIdx.x;
    if (e >= ETOT) return;
    int dst = (e < NE) ? ei[NE + e] : (e - NE);
    atomicAdd(&counts[dst], 1);
}

// phase 1: per-block exclusive scan of counts -> offsets (local), block sums
__global__ __launch_bounds__(SCAN_B) void k_scan1(const int* __restrict__ counts,
                                                  int* __restrict__ offsets,
                                                  int* __restrict__ blocksums) {
    __shared__ int sh[SCAN_B];
    int t = threadIdx.x;
    int i = blockIdx.x * SCAN_B + t;
    int v = (i < NN) ? counts[i] : 0;
    sh[t] = v;
    __syncthreads();
    #pragma unroll
    for (int off = 1; off < SCAN_B; off <<= 1) {
        int u = (t >= off) ? sh[t - off] : 0;
        __syncthreads();
        sh[t] += u;
        __syncthreads();
    }
    if (i < NN) offsets[i] = sh[t] - v;          // exclusive within block
    if (t == SCAN_B - 1) blocksums[blockIdx.x] = sh[t];
}

// phase 2: exclusive scan of the 196 block sums (single block)
__global__ __launch_bounds__(SCAN_B) void k_scan2(int* __restrict__ blocksums) {
    __shared__ int sh[SCAN_B];
    int t = threadIdx.x;
    int v = (t < SCAN_NBLK) ? blocksums[t] : 0;
    sh[t] = v;
    __syncthreads();
    #pragma unroll
    for (int off = 1; off < SCAN_B; off <<= 1) {
        int u = (t >= off) ? sh[t - off] : 0;
        __syncthreads();
        sh[t] += u;
        __syncthreads();
    }
    if (t < SCAN_NBLK) blocksums[t] = sh[t] - v; // exclusive
}

// phase 3: add block offsets; fill cursor; offsets[NN] = ETOT (constant)
__global__ void k_scan3(int* __restrict__ offsets, const int* __restrict__ blocksums,
                        int* __restrict__ cursor) {
    int i = blockIdx.x * blockDim.x + threadIdx.x;
    if (i < NN) {
        int off = offsets[i] + blocksums[i >> 8];
        offsets[i] = off;
        cursor[i] = off;
        if (i == 0) offsets[NN] = ETOT;
    }
}

__global__ void k_scatter(const int* __restrict__ ei, int* __restrict__ cursor,
                          int* __restrict__ sorted_src) {
    int e = blockIdx.x * blockDim.x + threadIdx.x;
    if (e >= ETOT) return;
    int src, dst;
    if (e < NE) { src = ei[e]; dst = ei[NE + e]; }
    else        { src = e - NE; dst = e - NE; }
    int pos = atomicAdd(&cursor[dst], 1);
    sorted_src[pos] = src;
}

// h1 = x @ W1   (x: [NN,128], W1: [128,128])
__global__ __launch_bounds__(256) void k_gemm1(const float* __restrict__ x,
                                               const float* __restrict__ W,
                                               float* __restrict__ h1) {
    __shared__ float Wl[128 * 128];   // 64 KB
    __shared__ float xs[128 * 68];    // transposed x tile, padded (34.8 KB)
    int t = threadIdx.x;
    int row0 = blockIdx.x * 64;
    #pragma unroll
    for (int i = 0; i < 16; ++i) {
        int idx = t * 4 + i * 1024;
        *(float4*)&Wl[idx] = *(const float4*)&W[idx];
    }
    #pragma unroll
    for (int i = 0; i < 8; ++i) {
        int flat = t * 4 + i * 1024;
        int r = flat >> 7, k = flat & 127;
        float4 v = make_float4(0.f, 0.f, 0.f, 0.f);
        if (row0 + r < NN) v = *(const float4*)&x[(size_t)(row0 + r) * 128 + k];
        xs[(k + 0) * 68 + r] = v.x;
        xs[(k + 1) * 68 + r] = v.y;
        xs[(k + 2) * 68 + r] = v.z;
        xs[(k + 3) * 68 + r] = v.w;
    }
    __syncthreads();
    int tr = t >> 4, tc = t & 15;
    int c0 = tc * 8;
    float acc[4][8];
    #pragma unroll
    for (int i = 0; i < 4; ++i)
        #pragma unroll
        for (int j = 0; j < 8; ++j) acc[i][j] = 0.f;
    #pragma unroll 8
    for (int k = 0; k < 128; ++k) {
        float4 a  = *(const float4*)&xs[k * 68 + tr * 4];
        float4 b0 = *(const float4*)&Wl[k * 128 + c0];
        float4 b1 = *(const float4*)&Wl[k * 128 + c0 + 4];
        float av[4] = {a.x, a.y, a.z, a.w};
        float bv[8] = {b0.x, b0.y, b0.z, b0.w, b1.x, b1.y, b1.z, b1.w};
        #pragma unroll
        for (int i = 0; i < 4; ++i)
            #pragma unroll
            for (int j = 0; j < 8; ++j) acc[i][j] = fmaf(av[i], bv[j], acc[i][j]);
    }
    #pragma unroll
    for (int i = 0; i < 4; ++i) {
        int r = row0 + tr * 4 + i;
        if (r < NN) {
            float4 o0 = make_float4(acc[i][0], acc[i][1], acc[i][2], acc[i][3]);
            float4 o1 = make_float4(acc[i][4], acc[i][5], acc[i][6], acc[i][7]);
            *(float4*)&h1[(size_t)r * 128 + c0] = o0;
            *(float4*)&h1[(size_t)r * 128 + c0 + 4] = o1;
        }
    }
}

// per-node attention coefficients for layer 1: es/ed [NN,4]
__global__ void k_att1(const float* __restrict__ h1, const float* __restrict__ a_src,
                       const float* __restrict__ a_dst, float* __restrict__ es,
                       float* __restrict__ ed) {
    int t = threadIdx.x;
    int node = blockIdx.x * 8 + (t >> 5);
    if (node >= NN) return;
    int j = t & 31;
    int head = j >> 3;
    int cb = (j * 4) & 31;
    float4 v = *(const float4*)&h1[(size_t)node * 128 + j * 4];
    float ps = v.x * a_src[head * 32 + cb]     + v.y * a_src[head * 32 + cb + 1]
             + v.z * a_src[head * 32 + cb + 2] + v.w * a_src[head * 32 + cb + 3];
    float pd = v.x * a_dst[head * 32 + cb]     + v.y * a_dst[head * 32 + cb + 1]
             + v.z * a_dst[head * 32 + cb + 2] + v.w * a_dst[head * 32 + cb + 3];
    #pragma unroll
    for (int off = 1; off < 8; off <<= 1) {
        ps += __shfl_xor(ps, off);
        pd += __shfl_xor(pd, off);
    }
    if ((j & 7) == 0) {
        es[node * 4 + head] = ps;
        ed[node * 4 + head] = pd;
    }
}

// layer-1 aggregation (online softmax) + bias + BN + ELU, wave per node
__global__ __launch_bounds__(256) void k_agg1(
        const float* __restrict__ h1, const float* __restrict__ es,
        const float* __restrict__ ed, const int* __restrict__ offsets,
        const int* __restrict__ sorted_src, const float* __restrict__ b1,
        const float* __restrict__ gamma, const float* __restrict__ beta,
        const float* __restrict__ mean, const float* __restrict__ var,
        float* __restrict__ hbn) {
    int node = blockIdx.x * 4 + (threadIdx.x >> 6);
    if (node >= NN) return;
    int l = threadIdx.x & 63;
    int head = l >> 4;
    int p0 = offsets[node], p1 = offsets[node + 1];
    float edv = ed[node * 4 + head];
    float m = -1e30f, s = 0.f, acc0 = 0.f, acc1 = 0.f;
    for (int p = p0; p < p1; ++p) {
        int srcn = sorted_src[p];
        float e = es[srcn * 4 + head] + edv;
        e = e > 0.f ? e : LEAKY * e;
        float mn = fmaxf(m, e);
        float scale = __expf(m - mn);
        float w = __expf(e - mn);
        float2 hv = *(const float2*)&h1[(size_t)srcn * 128 + 2 * l];
        s = s * scale + w;
        acc0 = acc0 * scale + w * hv.x;
        acc1 = acc1 * scale + w * hv.y;
        m = mn;
    }
    float inv = 1.f / s;
    int i0 = 2 * l, i1 = 2 * l + 1;
    float o0 = acc0 * inv + b1[i0];
    float o1 = acc1 * inv + b1[i1];
    o0 = (o0 - mean[i0]) * rsqrtf(var[i0] + BN_EPS) * gamma[i0] + beta[i0];
    o1 = (o1 - mean[i1]) * rsqrtf(var[i1] + BN_EPS) * gamma[i1] + beta[i1];
    o0 = o0 > 0.f ? o0 : __expf(o0) - 1.f;
    o1 = o1 > 0.f ? o1 : __expf(o1) - 1.f;
    *(float2*)&hbn[(size_t)node * 128 + 2 * l] = make_float2(o0, o1);
}

// h2 = hbn @ W2   (hbn: [NN,128], W2: [128,40])
__global__ __launch_bounds__(256) void k_gemm2(const float* __restrict__ hbn,
                                               const float* __restrict__ W,
                                               float* __restrict__ h2) {
    __shared__ float Wl[128 * 40];     // 20.5 KB
    __shared__ float xs[128 * 132];    // 67.6 KB
    int t = threadIdx.x;
    int row0 = blockIdx.x * 128;
    for (int i = t; i < 128 * 40 / 4; i += 256)
        *(float4*)&Wl[i * 4] = *(const float4*)&W[i * 4];
    #pragma unroll
    for (int i = 0; i < 16; ++i) {
        int flat = t * 4 + i * 1024;
        int r = flat >> 7, k = flat & 127;
        float4 v = make_float4(0.f, 0.f, 0.f, 0.f);
        if (row0 + r < NN) v = *(const float4*)&hbn[(size_t)(row0 + r) * 128 + k];
        xs[(k + 0) * 132 + r] = v.x;
        xs[(k + 1) * 132 + r] = v.y;
        xs[(k + 2) * 132 + r] = v.z;
        xs[(k + 3) * 132 + r] = v.w;
    }
    __syncthreads();
    int tr = t >> 3, tc = t & 7;   // 32 x 8
    int r0 = tr * 4, c0 = tc * 5;
    float acc[4][5];
    #pragma unroll
    for (int i = 0; i < 4; ++i)
        #pragma unroll
        for (int j = 0; j < 5; ++j) acc[i][j] = 0.f;
    #pragma unroll 4
    for (int k = 0; k < 128; ++k) {
        float4 a = *(const float4*)&xs[k * 132 + r0];
        float av[4] = {a.x, a.y, a.z, a.w};
        float bv[5];
        #pragma unroll
        for (int j = 0; j < 5; ++j) bv[j] = Wl[k * 40 + c0 + j];
        #pragma unroll
        for (int i = 0; i < 4; ++i)
            #pragma unroll
            for (int j = 0; j < 5; ++j) acc[i][j] = fmaf(av[i], bv[j], acc[i][j]);
    }
    #pragma unroll
    for (int i = 0; i < 4; ++i) {
        int r = row0 + r0 + i;
        if (r < NN) {
            #pragma unroll
            for (int j = 0; j < 5; ++j) h2[(size_t)r * 40 + c0 + j] = acc[i][j];
        }
    }
}

// per-node attention coefficients layer 2
__global__ void k_att2(const float* __restrict__ h2, const float* __restrict__ a_src,
                       const float* __restrict__ a_dst, float* __restrict__ es,
                       float* __restrict__ ed) {
    int node = blockIdx.x * 4 + (threadIdx.x >> 6);
    if (node >= NN) return;
    int l = threadIdx.x & 63;
    float ps = 0.f, pd = 0.f;
    if (l < 40) {
        float v = h2[(size_t)node * 40 + l];
        ps = v * a_src[l];
        pd = v * a_dst[l];
    }
    #pragma unroll
    for (int off = 1; off < 64; off <<= 1) {
        ps += __shfl_xor(ps, off);
        pd += __shfl_xor(pd, off);
    }
    if (l == 0) { es[node] = ps; ed[node] = pd; }
}

// layer-2 aggregation + bias + log_softmax, wave per node
__global__ __launch_bounds__(256) void k_agg2(
        const float* __restrict__ h2, const float* __restrict__ es,
        const float* __restrict__ ed, const int* __restrict__ offsets,
        const int* __restrict__ sorted_src, const float* __restrict__ b2,
        float* __restrict__ out) {
    int node = blockIdx.x * 4 + (threadIdx.x >> 6);
    if (node >= NN) return;
    int l = threadIdx.x & 63;
    int p0 = offsets[node], p1 = offsets[node + 1];
    float edv = ed[node];
    float m = -1e30f, s = 0.f, acc = 0.f;
    for (int p = p0; p < p1; ++p) {
        int srcn = sorted_src[p];
        float e = es[srcn] + edv;
        e = e > 0.f ? e : LEAKY * e;
        float mn = fmaxf(m, e);
        float scale = __expf(m - mn);
        float w = __expf(e - mn);
        float hv = (l < 40) ? h2[(size_t)srcn * 40 + l] : 0.f;
        s = s * scale + w;
        acc = acc * scale + w * hv;
        m = mn;
    }
    float v = acc / s + ((l < 40) ? b2[l] : 0.f);
    float mv = (l < 40) ? v : -1e30f;
    #pragma unroll
    for (int off = 1; off < 64; off <<= 1) mv = fmaxf(mv, __shfl_xor(mv, off));
    float ex = (l < 40) ? __expf(v - mv) : 0.f;
    #pragma unroll
    for (int off = 1; off < 64; off <<= 1) ex += __shfl_xor(ex, off);
    if (l < 40) out[(size_t)node * 40 + l] = v - mv - __logf(ex);
}

extern "C" void kernel_launch(void* const* d_in, const int* in_sizes, int n_in,
                              void* d_out, int out_size, void* d_ws, size_t ws_size,
                              hipStream_t stream) {
    const float* x   = (const float*)d_in[0];
    const int*   ei  = (const int*)d_in[1];
    const float* W1  = (const float*)d_in[2];
    const float* a1s = (const float*)d_in[3];
    const float* a1d = (const float*)d_in[4];
    const float* b1  = (const float*)d_in[5];
    const float* bng = (const float*)d_in[6];
    const float* bnb = (const float*)d_in[7];
    const float* bnm = (const float*)d_in[8];
    const float* bnv = (const float*)d_in[9];
    const float* W2  = (const float*)d_in[10];
    const float* a2s = (const float*)d_in[11];
    const float* a2d = (const float*)d_in[12];
    const float* b2  = (const float*)d_in[13];
    float* out = (float*)d_out;

    char* ws = (char*)d_ws;
    size_t off = 0;
    auto alloc = [&](size_t bytes) -> void* {
        void* p = ws + off;
        off = (off + bytes + 255) & ~(size_t)255;
        return p;
    };
    int*   counts   = (int*)alloc((size_t)NN * 4);
    int*   cursor   = (int*)alloc((size_t)NN * 4);
    int*   offsets  = (int*)alloc((size_t)(NN + 1) * 4);
    int*   ssrc     = (int*)alloc((size_t)ETOT * 4);
    int*   blocksum = (int*)alloc((size_t)SCAN_NBLK * 4);
    float* h1       = (float*)alloc((size_t)NN * 128 * 4);
    float* es1      = (float*)alloc((size_t)NN * 4 * 4);
    float* ed1      = (float*)alloc((size_t)NN * 4 * 4);
    float* hbn      = (float*)alloc((size_t)NN * 128 * 4);
    float* h2       = (float*)alloc((size_t)NN * 40 * 4);
    float* es2      = (float*)alloc((size_t)NN * 4);
    float* ed2      = (float*)alloc((size_t)NN * 4);

    k_zero<<<(NN + 255) / 256, 256, 0, stream>>>(counts, NN);
    k_count<<<(ETOT + 255) / 256, 256, 0, stream>>>(ei, counts);
    k_scan1<<<SCAN_NBLK, SCAN_B, 0, stream>>>(counts, offsets, blocksum);
    k_scan2<<<1, SCAN_B, 0, stream>>>(blocksum);
    k_scan3<<<(NN + 255) / 256, 256, 0, stream>>>(offsets, blocksum, cursor);
    k_scatter<<<(ETOT + 255) / 256, 256, 0, stream>>>(ei, cursor, ssrc);
    k_gemm1<<<(NN + 63) / 64, 256, 0, stream>>>(x, W1, h1);
    k_att1<<<(NN + 7) / 8, 256, 0, stream>>>(h1, a1s, a1d, es1, ed1);
    k_agg1<<<(NN + 3) / 4, 256, 0, stream>>>(h1, es1, ed1, offsets, ssrc,
                                             b1, bng, bnb, bnm, bnv, hbn);
    k_gemm2<<<(NN + 127) / 128, 256, 0, stream>>>(hbn, W2, h2);
    k_att2<<<(NN + 3) / 4, 256, 0, stream>>>(h2, a2s, a2d, es2, ed2);
    k_agg2<<<(NN + 3) / 4, 256, 0, stream>>>(h2, es2, ed2, offsets, ssrc, b2, out);
}

// Round 3
// 269.312 us; speedup vs baseline: 1.8024x; 1.4309x over previous
//
#include <hip/hip_runtime.h>
#include <hip/hip_bf16.h>
#include <math.h>

#define NN 50000
#define NE 800000
#define ETOT (NE + NN)
#define LEAKY 0.2f
#define BN_EPS 1e-5f

#define SCAN_B 256
#define SCAN_NBLK ((NN + SCAN_B - 1) / SCAN_B)   // 196

typedef unsigned short u16;
typedef unsigned int u32;

__device__ __forceinline__ float bf2f(u32 u) {
    union { u32 i; float f; } x; x.i = u << 16; return x.f;
}
__device__ __forceinline__ u16 f2bf(float f) {
    __hip_bfloat16 b = __float2bfloat16(f);
    return *reinterpret_cast<u16*>(&b);
}

__global__ void k_zero(int* __restrict__ p, int n) {
    int i = blockIdx.x * blockDim.x + threadIdx.x;
    if (i < n) p[i] = 0;
}

__global__ void k_count(const int* __restrict__ ei, int* __restrict__ counts) {
    int e = blockIdx.x * blockDim.x + threadIdx.x;
    if (e >= ETOT) return;
    int dst = (e < NE) ? ei[NE + e] : (e - NE);
    atomicAdd(&counts[dst], 1);
}

__global__ __launch_bounds__(SCAN_B) void k_scan1(const int* __restrict__ counts,
                                                  int* __restrict__ offsets,
                                                  int* __restrict__ blocksums) {
    __shared__ int sh[SCAN_B];
    int t = threadIdx.x;
    int i = blockIdx.x * SCAN_B + t;
    int v = (i < NN) ? counts[i] : 0;
    sh[t] = v;
    __syncthreads();
    #pragma unroll
    for (int off = 1; off < SCAN_B; off <<= 1) {
        int u = (t >= off) ? sh[t - off] : 0;
        __syncthreads();
        sh[t] += u;
        __syncthreads();
    }
    if (i < NN) offsets[i] = sh[t] - v;
    if (t == SCAN_B - 1) blocksums[blockIdx.x] = sh[t];
}

__global__ __launch_bounds__(SCAN_B) void k_scan2(int* __restrict__ blocksums) {
    __shared__ int sh[SCAN_B];
    int t = threadIdx.x;
    int v = (t < SCAN_NBLK) ? blocksums[t] : 0;
    sh[t] = v;
    __syncthreads();
    #pragma unroll
    for (int off = 1; off < SCAN_B; off <<= 1) {
        int u = (t >= off) ? sh[t - off] : 0;
        __syncthreads();
        sh[t] += u;
        __syncthreads();
    }
    if (t < SCAN_NBLK) blocksums[t] = sh[t] - v;
}

__global__ void k_scan3(int* __restrict__ offsets, const int* __restrict__ blocksums,
                        int* __restrict__ cursor) {
    int i = blockIdx.x * blockDim.x + threadIdx.x;
    if (i < NN) {
        int off = offsets[i] + blocksums[i >> 8];
        offsets[i] = off;
        cursor[i] = off;
        if (i == 0) offsets[NN] = ETOT;
    }
}

__global__ void k_scatter(const int* __restrict__ ei, int* __restrict__ cursor,
                          int* __restrict__ sorted_src) {
    int e = blockIdx.x * blockDim.x + threadIdx.x;
    if (e >= ETOT) return;
    int src, dst;
    if (e < NE) { src = ei[e]; dst = ei[NE + e]; }
    else        { src = e - NE; dst = e - NE; }
    int pos = atomicAdd(&cursor[dst], 1);
    sorted_src[pos] = src;
}

// h1b (bf16) = x @ W1   (x: [NN,128], W1: [128,128])
__global__ __launch_bounds__(256) void k_gemm1(const float* __restrict__ x,
                                               const float* __restrict__ W,
                                               u16* __restrict__ h1b) {
    __shared__ float Wl[128 * 128];
    __shared__ float xs[128 * 68];
    int t = threadIdx.x;
    int row0 = blockIdx.x * 64;
    #pragma unroll
    for (int i = 0; i < 16; ++i) {
        int idx = t * 4 + i * 1024;
        *(float4*)&Wl[idx] = *(const float4*)&W[idx];
    }
    #pragma unroll
    for (int i = 0; i < 8; ++i) {
        int flat = t * 4 + i * 1024;
        int r = flat >> 7, k = flat & 127;
        float4 v = make_float4(0.f, 0.f, 0.f, 0.f);
        if (row0 + r < NN) v = *(const float4*)&x[(size_t)(row0 + r) * 128 + k];
        xs[(k + 0) * 68 + r] = v.x;
        xs[(k + 1) * 68 + r] = v.y;
        xs[(k + 2) * 68 + r] = v.z;
        xs[(k + 3) * 68 + r] = v.w;
    }
    __syncthreads();
    int tr = t >> 4, tc = t & 15;
    int c0 = tc * 8;
    float acc[4][8];
    #pragma unroll
    for (int i = 0; i < 4; ++i)
        #pragma unroll
        for (int j = 0; j < 8; ++j) acc[i][j] = 0.f;
    #pragma unroll 8
    for (int k = 0; k < 128; ++k) {
        float4 a  = *(const float4*)&xs[k * 68 + tr * 4];
        float4 b0 = *(const float4*)&Wl[k * 128 + c0];
        float4 b1 = *(const float4*)&Wl[k * 128 + c0 + 4];
        float av[4] = {a.x, a.y, a.z, a.w};
        float bv[8] = {b0.x, b0.y, b0.z, b0.w, b1.x, b1.y, b1.z, b1.w};
        #pragma unroll
        for (int i = 0; i < 4; ++i)
            #pragma unroll
            for (int j = 0; j < 8; ++j) acc[i][j] = fmaf(av[i], bv[j], acc[i][j]);
    }
    #pragma unroll
    for (int i = 0; i < 4; ++i) {
        int r = row0 + tr * 4 + i;
        if (r < NN) {
            union { u16 u[8]; uint4 v; } pk;
            #pragma unroll
            for (int j = 0; j < 8; ++j) pk.u[j] = f2bf(acc[i][j]);
            *(uint4*)&h1b[(size_t)r * 128 + c0] = pk.v;
        }
    }
}

// per-node attention coefficients layer 1 (from bf16 h1)
__global__ void k_att1(const u16* __restrict__ h1b, const float* __restrict__ a_src,
                       const float* __restrict__ a_dst, float* __restrict__ es,
                       float* __restrict__ ed) {
    int t = threadIdx.x;
    int node = blockIdx.x * 8 + (t >> 5);
    if (node >= NN) return;
    int j = t & 31;
    int head = j >> 3;
    int cb = (j * 4) & 31;
    uint2 raw = *(const uint2*)&h1b[(size_t)node * 128 + j * 4];
    float v0 = bf2f(raw.x & 0xffffu), v1 = bf2f(raw.x >> 16);
    float v2 = bf2f(raw.y & 0xffffu), v3 = bf2f(raw.y >> 16);
    float ps = v0 * a_src[head * 32 + cb]     + v1 * a_src[head * 32 + cb + 1]
             + v2 * a_src[head * 32 + cb + 2] + v3 * a_src[head * 32 + cb + 3];
    float pd = v0 * a_dst[head * 32 + cb]     + v1 * a_dst[head * 32 + cb + 1]
             + v2 * a_dst[head * 32 + cb + 2] + v3 * a_dst[head * 32 + cb + 3];
    #pragma unroll
    for (int off = 1; off < 8; off <<= 1) {
        ps += __shfl_xor(ps, off);
        pd += __shfl_xor(pd, off);
    }
    if ((j & 7) == 0) {
        es[node * 4 + head] = ps;
        ed[node * 4 + head] = pd;
    }
}

// layer-1 aggregation (plain-exp softmax, batched gather) + bias + BN + ELU
__global__ __launch_bounds__(256) void k_agg1(
        const u16* __restrict__ h1b, const float* __restrict__ es,
        const float* __restrict__ ed, const int* __restrict__ offsets,
        const int* __restrict__ ssrc, const float* __restrict__ b1,
        const float* __restrict__ gamma, const float* __restrict__ beta,
        const float* __restrict__ mean, const float* __restrict__ var,
        float* __restrict__ hbn) {
    int node = blockIdx.x * 4 + (threadIdx.x >> 6);
    if (node >= NN) return;
    int l = threadIdx.x & 63;
    int head = l >> 4;
    int p0 = offsets[node], p1 = offsets[node + 1];
    float edv = ed[node * 4 + head];
    float s = 0.f, acc0 = 0.f, acc1 = 0.f;
    for (int base = p0; base < p1; base += 64) {
        int cnt = min(64, p1 - base);
        int myidx = (l < cnt) ? ssrc[base + l] : 0;
        int j = 0;
        for (; j + 4 <= cnt; j += 4) {
            int s0 = __shfl(myidx, j);
            int s1 = __shfl(myidx, j + 1);
            int s2 = __shfl(myidx, j + 2);
            int s3 = __shfl(myidx, j + 3);
            u32 w0 = *(const u32*)&h1b[(size_t)s0 * 128 + 2 * l];
            u32 w1 = *(const u32*)&h1b[(size_t)s1 * 128 + 2 * l];
            u32 w2 = *(const u32*)&h1b[(size_t)s2 * 128 + 2 * l];
            u32 w3 = *(const u32*)&h1b[(size_t)s3 * 128 + 2 * l];
            float e0 = es[s0 * 4 + head] + edv;
            float e1 = es[s1 * 4 + head] + edv;
            float e2 = es[s2 * 4 + head] + edv;
            float e3 = es[s3 * 4 + head] + edv;
            e0 = e0 > 0.f ? e0 : LEAKY * e0;  float x0 = __expf(e0);
            e1 = e1 > 0.f ? e1 : LEAKY * e1;  float x1 = __expf(e1);
            e2 = e2 > 0.f ? e2 : LEAKY * e2;  float x2 = __expf(e2);
            e3 = e3 > 0.f ? e3 : LEAKY * e3;  float x3 = __expf(e3);
            s += (x0 + x1) + (x2 + x3);
            acc0 = fmaf(x0, bf2f(w0 & 0xffffu), acc0);
            acc1 = fmaf(x0, bf2f(w0 >> 16), acc1);
            acc0 = fmaf(x1, bf2f(w1 & 0xffffu), acc0);
            acc1 = fmaf(x1, bf2f(w1 >> 16), acc1);
            acc0 = fmaf(x2, bf2f(w2 & 0xffffu), acc0);
            acc1 = fmaf(x2, bf2f(w2 >> 16), acc1);
            acc0 = fmaf(x3, bf2f(w3 & 0xffffu), acc0);
            acc1 = fmaf(x3, bf2f(w3 >> 16), acc1);
        }
        for (; j < cnt; ++j) {
            int s0 = __shfl(myidx, j);
            u32 w0 = *(const u32*)&h1b[(size_t)s0 * 128 + 2 * l];
            float e0 = es[s0 * 4 + head] + edv;
            e0 = e0 > 0.f ? e0 : LEAKY * e0;
            float x0 = __expf(e0);
            s += x0;
            acc0 = fmaf(x0, bf2f(w0 & 0xffffu), acc0);
            acc1 = fmaf(x0, bf2f(w0 >> 16), acc1);
        }
    }
    float inv = 1.f / s;
    int i0 = 2 * l, i1 = 2 * l + 1;
    float o0 = acc0 * inv + b1[i0];
    float o1 = acc1 * inv + b1[i1];
    o0 = (o0 - mean[i0]) * rsqrtf(var[i0] + BN_EPS) * gamma[i0] + beta[i0];
    o1 = (o1 - mean[i1]) * rsqrtf(var[i1] + BN_EPS) * gamma[i1] + beta[i1];
    o0 = o0 > 0.f ? o0 : __expf(o0) - 1.f;
    o1 = o1 > 0.f ? o1 : __expf(o1) - 1.f;
    *(float2*)&hbn[(size_t)node * 128 + 2 * l] = make_float2(o0, o1);
}

// h2 = hbn @ W2   (hbn: [NN,128], W2: [128,40])
__global__ __launch_bounds__(256) void k_gemm2(const float* __restrict__ hbn,
                                               const float* __restrict__ W,
                                               float* __restrict__ h2) {
    __shared__ float Wl[128 * 40];
    __shared__ float xs[128 * 132];
    int t = threadIdx.x;
    int row0 = blockIdx.x * 128;
    for (int i = t; i < 128 * 40 / 4; i += 256)
        *(float4*)&Wl[i * 4] = *(const float4*)&W[i * 4];
    #pragma unroll
    for (int i = 0; i < 16; ++i) {
        int flat = t * 4 + i * 1024;
        int r = flat >> 7, k = flat & 127;
        float4 v = make_float4(0.f, 0.f, 0.f, 0.f);
        if (row0 + r < NN) v = *(const float4*)&hbn[(size_t)(row0 + r) * 128 + k];
        xs[(k + 0) * 132 + r] = v.x;
        xs[(k + 1) * 132 + r] = v.y;
        xs[(k + 2) * 132 + r] = v.z;
        xs[(k + 3) * 132 + r] = v.w;
    }
    __syncthreads();
    int tr = t >> 3, tc = t & 7;
    int r0 = tr * 4, c0 = tc * 5;
    float acc[4][5];
    #pragma unroll
    for (int i = 0; i < 4; ++i)
        #pragma unroll
        for (int j = 0; j < 5; ++j) acc[i][j] = 0.f;
    #pragma unroll 4
    for (int k = 0; k < 128; ++k) {
        float4 a = *(const float4*)&xs[k * 132 + r0];
        float av[4] = {a.x, a.y, a.z, a.w};
        float bv[5];
        #pragma unroll
        for (int j = 0; j < 5; ++j) bv[j] = Wl[k * 40 + c0 + j];
        #pragma unroll
        for (int i = 0; i < 4; ++i)
            #pragma unroll
            for (int j = 0; j < 5; ++j) acc[i][j] = fmaf(av[i], bv[j], acc[i][j]);
    }
    #pragma unroll
    for (int i = 0; i < 4; ++i) {
        int r = row0 + r0 + i;
        if (r < NN) {
            #pragma unroll
            for (int j = 0; j < 5; ++j) h2[(size_t)r * 40 + c0 + j] = acc[i][j];
        }
    }
}

__global__ void k_att2(const float* __restrict__ h2, const float* __restrict__ a_src,
                       const float* __restrict__ a_dst, float* __restrict__ es,
                       float* __restrict__ ed) {
    int node = blockIdx.x * 4 + (threadIdx.x >> 6);
    if (node >= NN) return;
    int l = threadIdx.x & 63;
    float ps = 0.f, pd = 0.f;
    if (l < 40) {
        float v = h2[(size_t)node * 40 + l];
        ps = v * a_src[l];
        pd = v * a_dst[l];
    }
    #pragma unroll
    for (int off = 1; off < 64; off <<= 1) {
        ps += __shfl_xor(ps, off);
        pd += __shfl_xor(pd, off);
    }
    if (l == 0) { es[node] = ps; ed[node] = pd; }
}

// layer-2 aggregation (plain-exp softmax, batched gather) + bias + log_softmax
__global__ __launch_bounds__(256) void k_agg2(
        const float* __restrict__ h2, const float* __restrict__ es,
        const float* __restrict__ ed, const int* __restrict__ offsets,
        const int* __restrict__ ssrc, const float* __restrict__ b2,
        float* __restrict__ out) {
    int node = blockIdx.x * 4 + (threadIdx.x >> 6);
    if (node >= NN) return;
    int l = threadIdx.x & 63;
    int p0 = offsets[node], p1 = offsets[node + 1];
    float edv = ed[node];
    float s = 0.f, acc = 0.f;
    bool pay = (l < 40);
    for (int base = p0; base < p1; base += 64) {
        int cnt = min(64, p1 - base);
        int myidx = (l < cnt) ? ssrc[base + l] : 0;
        int j = 0;
        for (; j + 4 <= cnt; j += 4) {
            int s0 = __shfl(myidx, j);
            int s1 = __shfl(myidx, j + 1);
            int s2 = __shfl(myidx, j + 2);
            int s3 = __shfl(myidx, j + 3);
            float h0 = pay ? h2[(size_t)s0 * 40 + l] : 0.f;
            float h1v = pay ? h2[(size_t)s1 * 40 + l] : 0.f;
            float h2v = pay ? h2[(size_t)s2 * 40 + l] : 0.f;
            float h3 = pay ? h2[(size_t)s3 * 40 + l] : 0.f;
            float e0 = es[s0] + edv;
            float e1 = es[s1] + edv;
            float e2 = es[s2] + edv;
            float e3 = es[s3] + edv;
            e0 = e0 > 0.f ? e0 : LEAKY * e0;  float x0 = __expf(e0);
            e1 = e1 > 0.f ? e1 : LEAKY * e1;  float x1 = __expf(e1);
            e2 = e2 > 0.f ? e2 : LEAKY * e2;  float x2 = __expf(e2);
            e3 = e3 > 0.f ? e3 : LEAKY * e3;  float x3 = __expf(e3);
            s += (x0 + x1) + (x2 + x3);
            acc = fmaf(x0, h0, acc);
            acc = fmaf(x1, h1v, acc);
            acc = fmaf(x2, h2v, acc);
            acc = fmaf(x3, h3, acc);
        }
        for (; j < cnt; ++j) {
            int s0 = __shfl(myidx, j);
            float h0 = pay ? h2[(size_t)s0 * 40 + l] : 0.f;
            float e0 = es[s0] + edv;
            e0 = e0 > 0.f ? e0 : LEAKY * e0;
            float x0 = __expf(e0);
            s += x0;
            acc = fmaf(x0, h0, acc);
        }
    }
    float v = acc / s + (pay ? b2[l] : 0.f);
    float mv = pay ? v : -1e30f;
    #pragma unroll
    for (int off = 1; off < 64; off <<= 1) mv = fmaxf(mv, __shfl_xor(mv, off));
    float ex = pay ? __expf(v - mv) : 0.f;
    #pragma unroll
    for (int off = 1; off < 64; off <<= 1) ex += __shfl_xor(ex, off);
    if (pay) out[(size_t)node * 40 + l] = v - mv - __logf(ex);
}

extern "C" void kernel_launch(void* const* d_in, const int* in_sizes, int n_in,
                              void* d_out, int out_size, void* d_ws, size_t ws_size,
                              hipStream_t stream) {
    const float* x   = (const float*)d_in[0];
    const int*   ei  = (const int*)d_in[1];
    const float* W1  = (const float*)d_in[2];
    const float* a1s = (const float*)d_in[3];
    const float* a1d = (const float*)d_in[4];
    const float* b1  = (const float*)d_in[5];
    const float* bng = (const float*)d_in[6];
    const float* bnb = (const float*)d_in[7];
    const float* bnm = (const float*)d_in[8];
    const float* bnv = (const float*)d_in[9];
    const float* W2  = (const float*)d_in[10];
    const float* a2s = (const float*)d_in[11];
    const float* a2d = (const float*)d_in[12];
    const float* b2  = (const float*)d_in[13];
    float* out = (float*)d_out;

    char* ws = (char*)d_ws;
    size_t off = 0;
    auto alloc = [&](size_t bytes) -> void* {
        void* p = ws + off;
        off = (off + bytes + 255) & ~(size_t)255;
        return p;
    };
    int*   counts   = (int*)alloc((size_t)NN * 4);
    int*   cursor   = (int*)alloc((size_t)NN * 4);
    int*   offsets  = (int*)alloc((size_t)(NN + 1) * 4);
    int*   ssrc     = (int*)alloc((size_t)ETOT * 4);
    int*   blocksum = (int*)alloc((size_t)SCAN_NBLK * 4);
    u16*   h1b      = (u16*)alloc((size_t)NN * 128 * 2);
    float* es1      = (float*)alloc((size_t)NN * 4 * 4);
    float* ed1      = (float*)alloc((size_t)NN * 4 * 4);
    float* hbn      = (float*)alloc((size_t)NN * 128 * 4);
    float* h2      = (float*)alloc((size_t)NN * 40 * 4);
    float* es2      = (float*)alloc((size_t)NN * 4);
    float* ed2      = (float*)alloc((size_t)NN * 4);

    k_zero<<<(NN + 255) / 256, 256, 0, stream>>>(counts, NN);
    k_count<<<(ETOT + 255) / 256, 256, 0, stream>>>(ei, counts);
    k_scan1<<<SCAN_NBLK, SCAN_B, 0, stream>>>(counts, offsets, blocksum);
    k_scan2<<<1, SCAN_B, 0, stream>>>(blocksum);
    k_scan3<<<(NN + 255) / 256, 256, 0, stream>>>(offsets, blocksum, cursor);
    k_scatter<<<(ETOT + 255) / 256, 256, 0, stream>>>(ei, cursor, ssrc);
    k_gemm1<<<(NN + 63) / 64, 256, 0, stream>>>(x, W1, h1b);
    k_att1<<<(NN + 7) / 8, 256, 0, stream>>>(h1b, a1s, a1d, es1, ed1);
    k_agg1<<<(NN + 3) / 4, 256, 0, stream>>>(h1b, es1, ed1, offsets, ssrc,
                                             b1, bng, bnb, bnm, bnv, hbn);
    k_gemm2<<<(NN + 127) / 128, 256, 0, stream>>>(hbn, W2, h2);
    k_att2<<<(NN + 3) / 4, 256, 0, stream>>>(h2, a2s, a2d, es2, ed2);
    k_agg2<<<(NN + 3) / 4, 256, 0, stream>>>(h2, es2, ed2, offsets, ssrc, b2, out);
}

// Round 4
// 204.685 us; speedup vs baseline: 2.3714x; 1.3157x over previous
//
#include <hip/hip_runtime.h>
#include <hip/hip_bf16.h>
#include <math.h>

#define NN 50000
#define NE 800000
#define ETOT (NE + NN)
#define LEAKY 0.2f
#define BN_EPS 1e-5f

#define SCAN_B 256
#define SCAN_NBLK ((NN + SCAN_B - 1) / SCAN_B)   // 196

#define BN1 144   // 128 h1 cols + 4 es + 4 ed + 8 pad
#define BN2 48    // 40 h2 cols + es2 + ed2 + 6 pad

typedef unsigned short u16;
typedef unsigned int u32;
typedef short s16;
typedef __attribute__((ext_vector_type(8))) short bf16x8;
typedef __attribute__((ext_vector_type(4))) float f32x4;

__device__ __forceinline__ float bf2f(u32 u) {
    union { u32 i; float f; } x; x.i = u << 16; return x.f;
}
__device__ __forceinline__ u16 f2bf(float f) {
    __hip_bfloat16 b = __float2bfloat16(f);
    return *reinterpret_cast<u16*>(&b);
}

__global__ void k_count(const int* __restrict__ ei, int* __restrict__ counts) {
    int e = blockIdx.x * blockDim.x + threadIdx.x;
    if (e >= ETOT) return;
    int dst = (e < NE) ? ei[NE + e] : (e - NE);
    atomicAdd(&counts[dst], 1);
}

__global__ __launch_bounds__(SCAN_B) void k_scan1(const int* __restrict__ counts,
                                                  int* __restrict__ offsets,
                                                  int* __restrict__ blocksums) {
    __shared__ int sh[SCAN_B];
    int t = threadIdx.x;
    int i = blockIdx.x * SCAN_B + t;
    int v = (i < NN) ? counts[i] : 0;
    sh[t] = v;
    __syncthreads();
    #pragma unroll
    for (int off = 1; off < SCAN_B; off <<= 1) {
        int u = (t >= off) ? sh[t - off] : 0;
        __syncthreads();
        sh[t] += u;
        __syncthreads();
    }
    if (i < NN) offsets[i] = sh[t] - v;
    if (t == SCAN_B - 1) blocksums[blockIdx.x] = sh[t];
}

__global__ __launch_bounds__(SCAN_B) void k_scan2(int* __restrict__ blocksums) {
    __shared__ int sh[SCAN_B];
    int t = threadIdx.x;
    int v = (t < SCAN_NBLK) ? blocksums[t] : 0;
    sh[t] = v;
    __syncthreads();
    #pragma unroll
    for (int off = 1; off < SCAN_B; off <<= 1) {
        int u = (t >= off) ? sh[t - off] : 0;
        __syncthreads();
        sh[t] += u;
        __syncthreads();
    }
    if (t < SCAN_NBLK) blocksums[t] = sh[t] - v;
}

__global__ void k_scan3(int* __restrict__ offsets, const int* __restrict__ blocksums,
                        int* __restrict__ cursor) {
    int i = blockIdx.x * blockDim.x + threadIdx.x;
    if (i < NN) {
        int off = offsets[i] + blocksums[i >> 8];
        offsets[i] = off;
        cursor[i] = off;
        if (i == 0) offsets[NN] = ETOT;
    }
}

__global__ void k_scatter(const int* __restrict__ ei, int* __restrict__ cursor,
                          int* __restrict__ sorted_src) {
    int e = blockIdx.x * blockDim.x + threadIdx.x;
    if (e >= ETOT) return;
    int src, dst;
    if (e < NE) { src = ei[e]; dst = ei[NE + e]; }
    else        { src = e - NE; dst = e - NE; }
    int pos = atomicAdd(&cursor[dst], 1);
    sorted_src[pos] = src;
}

// Build transposed bf16 weight panels with fused attention-coefficient columns.
// Wt1[n][k], n in [0,144): n<128 -> W1[k][n]; 128..131 -> sum_c W1[k][h*32+c]*a1s;
// 132..135 -> a1d version; rest 0.  Wt2[n][k], n<40 -> W2[k][n]; 40/41 -> a2s/a2d.
__global__ void k_prep(const float* __restrict__ W1, const float* __restrict__ a1s,
                       const float* __restrict__ a1d, const float* __restrict__ W2,
                       const float* __restrict__ a2s, const float* __restrict__ a2d,
                       u16* __restrict__ Wt1, u16* __restrict__ Wt2) {
    int tid = blockIdx.x * blockDim.x + threadIdx.x;
    int nth = gridDim.x * blockDim.x;
    for (int idx = tid; idx < BN1 * 128; idx += nth) {
        int n = idx >> 7, k = idx & 127;
        float v = 0.f;
        if (n < 128) v = W1[k * 128 + n];
        else if (n < 132) {
            int h = n - 128; float s = 0.f;
            for (int c = 0; c < 32; ++c) s += W1[k * 128 + h * 32 + c] * a1s[h * 32 + c];
            v = s;
        } else if (n < 136) {
            int h = n - 132; float s = 0.f;
            for (int c = 0; c < 32; ++c) s += W1[k * 128 + h * 32 + c] * a1d[h * 32 + c];
            v = s;
        }
        Wt1[idx] = f2bf(v);
    }
    for (int idx = tid; idx < BN2 * 128; idx += nth) {
        int n = idx >> 7, k = idx & 127;
        float v = 0.f;
        if (n < 40) v = W2[k * 40 + n];
        else if (n == 40) { float s = 0.f; for (int c = 0; c < 40; ++c) s += W2[k * 40 + c] * a2s[c]; v = s; }
        else if (n == 41) { float s = 0.f; for (int c = 0; c < 40; ++c) s += W2[k * 40 + c] * a2d[c]; v = s; }
        Wt2[idx] = f2bf(v);
    }
}

// MFMA GEMM layer 1: h1b[NN,128] bf16 + es1/ed1[NN,4] fp32, from x fp32.
__global__ __launch_bounds__(256) void k_mm1(const float* __restrict__ x,
                                             const u16* __restrict__ Wt1,
                                             u16* __restrict__ h1b,
                                             float* __restrict__ es1,
                                             float* __restrict__ ed1) {
    __shared__ __align__(16) s16 As[128 * 128];   // [row][k] swizzled, 32KB
    __shared__ __align__(16) s16 Bs[BN1 * 128];   // [n][k] swizzled, 36.9KB
    int t = threadIdx.x;
    int row0 = blockIdx.x * 128;
    // stage A: x fp32 -> bf16; 4096 float4 chunks, coalesced; ds_write_b64
    #pragma unroll
    for (int i = 0; i < 16; ++i) {
        int c = t + i * 256;               // 0..4095
        int r = c >> 5, k0 = (c & 31) * 4;
        float4 v = make_float4(0.f, 0.f, 0.f, 0.f);
        int row = row0 + r;
        if (row < NN) v = *(const float4*)&x[(size_t)row * 128 + k0];
        u16 pk[4] = {f2bf(v.x), f2bf(v.y), f2bf(v.z), f2bf(v.w)};
        int byte = (r * 256 + k0 * 2) ^ ((r & 7) << 4);
        *(uint2*)((char*)As + byte) = *(uint2*)pk;
    }
    // stage B: 2304 16B chunks
    #pragma unroll
    for (int i = 0; i < 9; ++i) {
        int c = t + i * 256;               // 0..2303
        int n = c >> 4, k0 = (c & 15) * 8;
        uint4 v = *(const uint4*)&Wt1[n * 128 + k0];
        int byte = (n * 256 + k0 * 2) ^ ((n & 7) << 4);
        *(uint4*)((char*)Bs + byte) = v;
    }
    __syncthreads();
    int wave = t >> 6, lane = t & 63;
    int lr = lane & 15, lq = lane >> 4;
    int wrow = wave * 32;
    f32x4 acc[2][9];
    #pragma unroll
    for (int a = 0; a < 2; ++a)
        #pragma unroll
        for (int b = 0; b < 9; ++b) acc[a][b] = (f32x4){0.f, 0.f, 0.f, 0.f};
    #pragma unroll
    for (int ks = 0; ks < 4; ++ks) {
        int kb = ks * 32 + lq * 8;
        bf16x8 af[2];
        #pragma unroll
        for (int rb = 0; rb < 2; ++rb) {
            int r = wrow + rb * 16 + lr;
            int byte = (r * 256 + kb * 2) ^ ((r & 7) << 4);
            af[rb] = *(bf16x8*)((char*)As + byte);
        }
        #pragma unroll
        for (int cb = 0; cb < 9; ++cb) {
            int n = cb * 16 + lr;
            int byte = (n * 256 + kb * 2) ^ ((n & 7) << 4);
            bf16x8 bfr = *(bf16x8*)((char*)Bs + byte);
            acc[0][cb] = __builtin_amdgcn_mfma_f32_16x16x32_bf16(af[0], bfr, acc[0][cb], 0, 0, 0);
            acc[1][cb] = __builtin_amdgcn_mfma_f32_16x16x32_bf16(af[1], bfr, acc[1][cb], 0, 0, 0);
        }
    }
    // epilogue: C layout row=(lane>>4)*4+reg, col=lane&15
    #pragma unroll
    for (int rb = 0; rb < 2; ++rb) {
        #pragma unroll
        for (int cb = 0; cb < 9; ++cb) {
            #pragma unroll
            for (int r = 0; r < 4; ++r) {
                int row = row0 + wrow + rb * 16 + lq * 4 + r;
                int col = cb * 16 + lr;
                if (row < NN) {
                    float v = acc[rb][cb][r];
                    if (col < 128) h1b[(size_t)row * 128 + col] = f2bf(v);
                    else if (col < 132) es1[row * 4 + (col - 128)] = v;
                    else if (col < 136) ed1[row * 4 + (col - 132)] = v;
                }
            }
        }
    }
}

// MFMA GEMM layer 2: h2[NN,40] fp32 + es2/ed2[NN] fp32, from hbn_b bf16.
__global__ __launch_bounds__(256) void k_mm2(const u16* __restrict__ hbnb,
                                             const u16* __restrict__ Wt2,
                                             float* __restrict__ h2,
                                             float* __restrict__ es2,
                                             float* __restrict__ ed2) {
    __shared__ __align__(16) s16 As[128 * 128];   // 32KB
    __shared__ __align__(16) s16 Bs[BN2 * 128];   // 12.3KB
    int t = threadIdx.x;
    int row0 = blockIdx.x * 128;
    #pragma unroll
    for (int i = 0; i < 8; ++i) {
        int c = t + i * 256;               // 0..2047 16B chunks
        int r = c >> 4, k0 = (c & 15) * 8;
        uint4 v = make_uint4(0, 0, 0, 0);
        int row = row0 + r;
        if (row < NN) v = *(const uint4*)&hbnb[(size_t)row * 128 + k0];
        int byte = (r * 256 + k0 * 2) ^ ((r & 7) << 4);
        *(uint4*)((char*)As + byte) = v;
    }
    #pragma unroll
    for (int i = 0; i < 3; ++i) {
        int c = t + i * 256;               // 0..767
        int n = c >> 4, k0 = (c & 15) * 8;
        uint4 v = *(const uint4*)&Wt2[n * 128 + k0];
        int byte = (n * 256 + k0 * 2) ^ ((n & 7) << 4);
        *(uint4*)((char*)Bs + byte) = v;
    }
    __syncthreads();
    int wave = t >> 6, lane = t & 63;
    int lr = lane & 15, lq = lane >> 4;
    int wrow = wave * 32;
    f32x4 acc[2][3];
    #pragma unroll
    for (int a = 0; a < 2; ++a)
        #pragma unroll
        for (int b = 0; b < 3; ++b) acc[a][b] = (f32x4){0.f, 0.f, 0.f, 0.f};
    #pragma unroll
    for (int ks = 0; ks < 4; ++ks) {
        int kb = ks * 32 + lq * 8;
        bf16x8 af[2];
        #pragma unroll
        for (int rb = 0; rb < 2; ++rb) {
            int r = wrow + rb * 16 + lr;
            int byte = (r * 256 + kb * 2) ^ ((r & 7) << 4);
            af[rb] = *(bf16x8*)((char*)As + byte);
        }
        #pragma unroll
        for (int cb = 0; cb < 3; ++cb) {
            int n = cb * 16 + lr;
            int byte = (n * 256 + kb * 2) ^ ((n & 7) << 4);
            bf16x8 bfr = *(bf16x8*)((char*)Bs + byte);
            acc[0][cb] = __builtin_amdgcn_mfma_f32_16x16x32_bf16(af[0], bfr, acc[0][cb], 0, 0, 0);
            acc[1][cb] = __builtin_amdgcn_mfma_f32_16x16x32_bf16(af[1], bfr, acc[1][cb], 0, 0, 0);
        }
    }
    #pragma unroll
    for (int rb = 0; rb < 2; ++rb) {
        #pragma unroll
        for (int cb = 0; cb < 3; ++cb) {
            #pragma unroll
            for (int r = 0; r < 4; ++r) {
                int row = row0 + wrow + rb * 16 + lq * 4 + r;
                int col = cb * 16 + lr;
                if (row < NN) {
                    float v = acc[rb][cb][r];
                    if (col < 40) h2[(size_t)row * 40 + col] = v;
                    else if (col == 40) es2[row] = v;
                    else if (col == 41) ed2[row] = v;
                }
            }
        }
    }
}

// layer-1 aggregation (plain-exp softmax, batched gather) + bias + BN + ELU -> bf16
__global__ __launch_bounds__(256) void k_agg1(
        const u16* __restrict__ h1b, const float* __restrict__ es,
        const float* __restrict__ ed, const int* __restrict__ offsets,
        const int* __restrict__ ssrc, const float* __restrict__ b1,
        const float* __restrict__ gamma, const float* __restrict__ beta,
        const float* __restrict__ mean, const float* __restrict__ var,
        u16* __restrict__ hbnb) {
    int node = blockIdx.x * 4 + (threadIdx.x >> 6);
    if (node >= NN) return;
    int l = threadIdx.x & 63;
    int head = l >> 4;
    int p0 = offsets[node], p1 = offsets[node + 1];
    float edv = ed[node * 4 + head];
    float s = 0.f, acc0 = 0.f, acc1 = 0.f;
    for (int base = p0; base < p1; base += 64) {
        int cnt = min(64, p1 - base);
        int myidx = (l < cnt) ? ssrc[base + l] : 0;
        int j = 0;
        for (; j + 4 <= cnt; j += 4) {
            int s0 = __shfl(myidx, j);
            int s1 = __shfl(myidx, j + 1);
            int s2 = __shfl(myidx, j + 2);
            int s3 = __shfl(myidx, j + 3);
            u32 w0 = *(const u32*)&h1b[(size_t)s0 * 128 + 2 * l];
            u32 w1 = *(const u32*)&h1b[(size_t)s1 * 128 + 2 * l];
            u32 w2 = *(const u32*)&h1b[(size_t)s2 * 128 + 2 * l];
            u32 w3 = *(const u32*)&h1b[(size_t)s3 * 128 + 2 * l];
            float e0 = es[s0 * 4 + head] + edv;
            float e1 = es[s1 * 4 + head] + edv;
            float e2 = es[s2 * 4 + head] + edv;
            float e3 = es[s3 * 4 + head] + edv;
            e0 = e0 > 0.f ? e0 : LEAKY * e0;  float x0 = __expf(e0);
            e1 = e1 > 0.f ? e1 : LEAKY * e1;  float x1 = __expf(e1);
            e2 = e2 > 0.f ? e2 : LEAKY * e2;  float x2 = __expf(e2);
            e3 = e3 > 0.f ? e3 : LEAKY * e3;  float x3 = __expf(e3);
            s += (x0 + x1) + (x2 + x3);
            acc0 = fmaf(x0, bf2f(w0 & 0xffffu), acc0);
            acc1 = fmaf(x0, bf2f(w0 >> 16), acc1);
            acc0 = fmaf(x1, bf2f(w1 & 0xffffu), acc0);
            acc1 = fmaf(x1, bf2f(w1 >> 16), acc1);
            acc0 = fmaf(x2, bf2f(w2 & 0xffffu), acc0);
            acc1 = fmaf(x2, bf2f(w2 >> 16), acc1);
            acc0 = fmaf(x3, bf2f(w3 & 0xffffu), acc0);
            acc1 = fmaf(x3, bf2f(w3 >> 16), acc1);
        }
        for (; j < cnt; ++j) {
            int s0 = __shfl(myidx, j);
            u32 w0 = *(const u32*)&h1b[(size_t)s0 * 128 + 2 * l];
            float e0 = es[s0 * 4 + head] + edv;
            e0 = e0 > 0.f ? e0 : LEAKY * e0;
            float x0 = __expf(e0);
            s += x0;
            acc0 = fmaf(x0, bf2f(w0 & 0xffffu), acc0);
            acc1 = fmaf(x0, bf2f(w0 >> 16), acc1);
        }
    }
    float inv = 1.f / s;
    int i0 = 2 * l, i1 = 2 * l + 1;
    float o0 = acc0 * inv + b1[i0];
    float o1 = acc1 * inv + b1[i1];
    o0 = (o0 - mean[i0]) * rsqrtf(var[i0] + BN_EPS) * gamma[i0] + beta[i0];
    o1 = (o1 - mean[i1]) * rsqrtf(var[i1] + BN_EPS) * gamma[i1] + beta[i1];
    o0 = o0 > 0.f ? o0 : __expf(o0) - 1.f;
    o1 = o1 > 0.f ? o1 : __expf(o1) - 1.f;
    u32 pk = (u32)f2bf(o0) | ((u32)f2bf(o1) << 16);
    *(u32*)&hbnb[(size_t)node * 128 + 2 * l] = pk;
}

// layer-2 aggregation (plain-exp softmax, batched gather) + bias + log_softmax
__global__ __launch_bounds__(256) void k_agg2(
        const float* __restrict__ h2, const float* __restrict__ es,
        const float* __restrict__ ed, const int* __restrict__ offsets,
        const int* __restrict__ ssrc, const float* __restrict__ b2,
        float* __restrict__ out) {
    int node = blockIdx.x * 4 + (threadIdx.x >> 6);
    if (node >= NN) return;
    int l = threadIdx.x & 63;
    int p0 = offsets[node], p1 = offsets[node + 1];
    float edv = ed[node];
    float s = 0.f, acc = 0.f;
    bool pay = (l < 40);
    for (int base = p0; base < p1; base += 64) {
        int cnt = min(64, p1 - base);
        int myidx = (l < cnt) ? ssrc[base + l] : 0;
        int j = 0;
        for (; j + 4 <= cnt; j += 4) {
            int s0 = __shfl(myidx, j);
            int s1 = __shfl(myidx, j + 1);
            int s2 = __shfl(myidx, j + 2);
            int s3 = __shfl(myidx, j + 3);
            float h0 = pay ? h2[(size_t)s0 * 40 + l] : 0.f;
            float h1v = pay ? h2[(size_t)s1 * 40 + l] : 0.f;
            float h2v = pay ? h2[(size_t)s2 * 40 + l] : 0.f;
            float h3 = pay ? h2[(size_t)s3 * 40 + l] : 0.f;
            float e0 = es[s0] + edv;
            float e1 = es[s1] + edv;
            float e2 = es[s2] + edv;
            float e3 = es[s3] + edv;
            e0 = e0 > 0.f ? e0 : LEAKY * e0;  float x0 = __expf(e0);
            e1 = e1 > 0.f ? e1 : LEAKY * e1;  float x1 = __expf(e1);
            e2 = e2 > 0.f ? e2 : LEAKY * e2;  float x2 = __expf(e2);
            e3 = e3 > 0.f ? e3 : LEAKY * e3;  float x3 = __expf(e3);
            s += (x0 + x1) + (x2 + x3);
            acc = fmaf(x0, h0, acc);
            acc = fmaf(x1, h1v, acc);
            acc = fmaf(x2, h2v, acc);
            acc = fmaf(x3, h3, acc);
        }
        for (; j < cnt; ++j) {
            int s0 = __shfl(myidx, j);
            float h0 = pay ? h2[(size_t)s0 * 40 + l] : 0.f;
            float e0 = es[s0] + edv;
            e0 = e0 > 0.f ? e0 : LEAKY * e0;
            float x0 = __expf(e0);
            s += x0;
            acc = fmaf(x0, h0, acc);
        }
    }
    float v = acc / s + (pay ? b2[l] : 0.f);
    float mv = pay ? v : -1e30f;
    #pragma unroll
    for (int off = 1; off < 64; off <<= 1) mv = fmaxf(mv, __shfl_xor(mv, off));
    float ex = pay ? __expf(v - mv) : 0.f;
    #pragma unroll
    for (int off = 1; off < 64; off <<= 1) ex += __shfl_xor(ex, off);
    if (pay) out[(size_t)node * 40 + l] = v - mv - __logf(ex);
}

extern "C" void kernel_launch(void* const* d_in, const int* in_sizes, int n_in,
                              void* d_out, int out_size, void* d_ws, size_t ws_size,
                              hipStream_t stream) {
    const float* x   = (const float*)d_in[0];
    const int*   ei  = (const int*)d_in[1];
    const float* W1  = (const float*)d_in[2];
    const float* a1s = (const float*)d_in[3];
    const float* a1d = (const float*)d_in[4];
    const float* b1  = (const float*)d_in[5];
    const float* bng = (const float*)d_in[6];
    const float* bnb = (const float*)d_in[7];
    const float* bnm = (const float*)d_in[8];
    const float* bnv = (const float*)d_in[9];
    const float* W2  = (const float*)d_in[10];
    const float* a2s = (const float*)d_in[11];
    const float* a2d = (const float*)d_in[12];
    const float* b2  = (const float*)d_in[13];
    float* out = (float*)d_out;

    char* ws = (char*)d_ws;
    size_t off = 0;
    auto alloc = [&](size_t bytes) -> void* {
        void* p = ws + off;
        off = (off + bytes + 255) & ~(size_t)255;
        return p;
    };
    int*   counts   = (int*)alloc((size_t)NN * 4);
    int*   cursor   = (int*)alloc((size_t)NN * 4);
    int*   offsets  = (int*)alloc((size_t)(NN + 1) * 4);
    int*   ssrc     = (int*)alloc((size_t)ETOT * 4);
    int*   blocksum = (int*)alloc((size_t)SCAN_NBLK * 4);
    u16*   Wt1      = (u16*)alloc((size_t)BN1 * 128 * 2);
    u16*   Wt2      = (u16*)alloc((size_t)BN2 * 128 * 2);
    u16*   h1b      = (u16*)alloc((size_t)NN * 128 * 2);
    float* es1      = (float*)alloc((size_t)NN * 4 * 4);
    float* ed1      = (float*)alloc((size_t)NN * 4 * 4);
    u16*   hbnb     = (u16*)alloc((size_t)NN * 128 * 2);
    float* h2       = (float*)alloc((size_t)NN * 40 * 4);
    float* es2      = (float*)alloc((size_t)NN * 4);
    float* ed2      = (float*)alloc((size_t)NN * 4);

    hipMemsetAsync(counts, 0, (size_t)NN * 4, stream);
    k_prep<<<80, 256, 0, stream>>>(W1, a1s, a1d, W2, a2s, a2d, Wt1, Wt2);
    k_count<<<(ETOT + 255) / 256, 256, 0, stream>>>(ei, counts);
    k_scan1<<<SCAN_NBLK, SCAN_B, 0, stream>>>(counts, offsets, blocksum);
    k_scan2<<<1, SCAN_B, 0, stream>>>(blocksum);
    k_scan3<<<(NN + 255) / 256, 256, 0, stream>>>(offsets, blocksum, cursor);
    k_scatter<<<(ETOT + 255) / 256, 256, 0, stream>>>(ei, cursor, ssrc);
    k_mm1<<<(NN + 127) / 128, 256, 0, stream>>>(x, Wt1, h1b, es1, ed1);
    k_agg1<<<(NN + 3) / 4, 256, 0, stream>>>(h1b, es1, ed1, offsets, ssrc,
                                             b1, bng, bnb, bnm, bnv, hbnb);
    k_mm2<<<(NN + 127) / 128, 256, 0, stream>>>(hbnb, Wt2, h2, es2, ed2);
    k_agg2<<<(NN + 3) / 4, 256, 0, stream>>>(h2, es2, ed2, offsets, ssrc, b2, out);
}

// Round 5
// 149.039 us; speedup vs baseline: 3.2569x; 1.3734x over previous
//
#include <hip/hip_runtime.h>
#include <hip/hip_bf16.h>
#include <math.h>

#define NN 50000
#define NE 800000
#define ETOT (NE + NN)
#define LEAKY 0.2f
#define BN_EPS 1e-5f

#define NB 256      // dst buckets
#define BSZ 196     // nodes per bucket (256*196 = 50176 >= NN)
#define NBB 128     // binning blocks
#define EPB ((ETOT + NBB - 1) / NBB)

#define BN1 144   // 128 h1 cols + 4 es + 4 ed + 8 pad
#define BN2 48    // 40 h2 cols + es2 + ed2 + 6 pad

typedef unsigned short u16;
typedef unsigned int u32;
typedef short s16;
typedef __attribute__((ext_vector_type(8))) short bf16x8;
typedef __attribute__((ext_vector_type(4))) float f32x4;

__device__ __forceinline__ float bf2f(u32 u) {
    union { u32 i; float f; } x; x.i = u << 16; return x.f;
}
__device__ __forceinline__ u16 f2bf(float f) {
    __hip_bfloat16 b = __float2bfloat16(f);
    return *reinterpret_cast<u16*>(&b);
}

// ---- CSR build: bucket-local, write-combining friendly ----

// Pass A: per-(block,bucket) histogram
__global__ __launch_bounds__(256) void k_binA(const int* __restrict__ ei,
                                              int* __restrict__ cnt) {
    __shared__ int hist[NB];
    int t = threadIdx.x;
    for (int i = t; i < NB; i += 256) hist[i] = 0;
    __syncthreads();
    int e0 = blockIdx.x * EPB, e1 = min(e0 + EPB, ETOT);
    for (int e = e0 + t; e < e1; e += 256) {
        int dst = (e < NE) ? ei[NE + e] : (e - NE);
        atomicAdd(&hist[dst / BSZ], 1);
    }
    __syncthreads();
    for (int b = t; b < NB; b += 256) cnt[b * NBB + blockIdx.x] = hist[b];
}

// generic 3-phase exclusive scan (n <= 256*256, in -> out)
__global__ __launch_bounds__(256) void k_scanA(const int* __restrict__ in,
                                               int* __restrict__ out,
                                               int* __restrict__ bsums, int n) {
    __shared__ int sh[256];
    int t = threadIdx.x;
    int i = blockIdx.x * 256 + t;
    int v = (i < n) ? in[i] : 0;
    sh[t] = v;
    __syncthreads();
    #pragma unroll
    for (int off = 1; off < 256; off <<= 1) {
        int u = (t >= off) ? sh[t - off] : 0;
        __syncthreads();
        sh[t] += u;
        __syncthreads();
    }
    if (i < n) out[i] = sh[t] - v;
    if (t == 255) bsums[blockIdx.x] = sh[t];
}

__global__ __launch_bounds__(256) void k_scanB(int* __restrict__ bsums, int nb) {
    __shared__ int sh[256];
    int t = threadIdx.x;
    int v = (t < nb) ? bsums[t] : 0;
    sh[t] = v;
    __syncthreads();
    #pragma unroll
    for (int off = 1; off < 256; off <<= 1) {
        int u = (t >= off) ? sh[t - off] : 0;
        __syncthreads();
        sh[t] += u;
        __syncthreads();
    }
    if (t < nb) bsums[t] = sh[t] - v;
}

__global__ void k_scanC(int* __restrict__ out, const int* __restrict__ bsums, int n) {
    int i = blockIdx.x * blockDim.x + threadIdx.x;
    if (i < n) out[i] += bsums[i >> 8];
}

// Pass B: scatter packed (src<<16|dst) into bucket-grouped runs
__global__ __launch_bounds__(256) void k_binB(const int* __restrict__ ei,
                                              const int* __restrict__ excl,
                                              u32* __restrict__ packed) {
    __shared__ int cur[NB];
    int t = threadIdx.x;
    for (int b = t; b < NB; b += 256) cur[b] = excl[b * NBB + blockIdx.x];
    __syncthreads();
    int e0 = blockIdx.x * EPB, e1 = min(e0 + EPB, ETOT);
    for (int e = e0 + t; e < e1; e += 256) {
        int src, dst;
        if (e < NE) { src = ei[e]; dst = ei[NE + e]; }
        else        { src = e - NE; dst = e - NE; }
        int pos = atomicAdd(&cur[dst / BSZ], 1);
        packed[pos] = ((u32)src << 16) | (u32)dst;
    }
}

// Pass C: one block per bucket: per-dst histogram + scan -> offsets + final ssrc
__global__ __launch_bounds__(256) void k_binC(const u32* __restrict__ packed,
                                              const int* __restrict__ excl,
                                              int* __restrict__ offsets,
                                              int* __restrict__ ssrc) {
    __shared__ int hist[256];
    __shared__ int sc[256];
    __shared__ int cur[256];
    int b = blockIdx.x, t = threadIdx.x;
    int n0 = b * BSZ;
    int base = excl[b * NBB];
    int next = (b < NB - 1) ? excl[(b + 1) * NBB] : ETOT;
    int total = next - base;
    hist[t] = 0;
    __syncthreads();
    for (int i = t; i < total; i += 256) {
        int dst = (int)(packed[base + i] & 0xffffu);
        atomicAdd(&hist[dst - n0], 1);
    }
    __syncthreads();
    int v = hist[t];
    sc[t] = v;
    __syncthreads();
    #pragma unroll
    for (int off = 1; off < 256; off <<= 1) {
        int u = (t >= off) ? sc[t - off] : 0;
        __syncthreads();
        sc[t] += u;
        __syncthreads();
    }
    int exl = sc[t] - v;
    int node = n0 + t;
    if (t <= BSZ && node <= NN) {
        // t==BSZ only matters for the (never-taken) case; node<=NN guards tail
        if (t < BSZ || node == NN) offsets[node] = base + exl;
    }
    cur[t] = exl;
    __syncthreads();
    for (int i = t; i < total; i += 256) {
        u32 pv = packed[base + i];
        int dst = (int)(pv & 0xffffu);
        int pos = atomicAdd(&cur[dst - n0], 1);
        ssrc[base + pos] = (int)(pv >> 16);
    }
}

// ---- weight prep (fused attention-coefficient columns) ----
__global__ void k_prep(const float* __restrict__ W1, const float* __restrict__ a1s,
                       const float* __restrict__ a1d, const float* __restrict__ W2,
                       const float* __restrict__ a2s, const float* __restrict__ a2d,
                       u16* __restrict__ Wt1, u16* __restrict__ Wt2) {
    int tid = blockIdx.x * blockDim.x + threadIdx.x;
    int nth = gridDim.x * blockDim.x;
    for (int idx = tid; idx < BN1 * 128; idx += nth) {
        int n = idx >> 7, k = idx & 127;
        float v = 0.f;
        if (n < 128) v = W1[k * 128 + n];
        else if (n < 132) {
            int h = n - 128; float s = 0.f;
            for (int c = 0; c < 32; ++c) s += W1[k * 128 + h * 32 + c] * a1s[h * 32 + c];
            v = s;
        } else if (n < 136) {
            int h = n - 132; float s = 0.f;
            for (int c = 0; c < 32; ++c) s += W1[k * 128 + h * 32 + c] * a1d[h * 32 + c];
            v = s;
        }
        Wt1[idx] = f2bf(v);
    }
    for (int idx = tid; idx < BN2 * 128; idx += nth) {
        int n = idx >> 7, k = idx & 127;
        float v = 0.f;
        if (n < 40) v = W2[k * 40 + n];
        else if (n == 40) { float s = 0.f; for (int c = 0; c < 40; ++c) s += W2[k * 40 + c] * a2s[c]; v = s; }
        else if (n == 41) { float s = 0.f; for (int c = 0; c < 40; ++c) s += W2[k * 40 + c] * a2d[c]; v = s; }
        Wt2[idx] = f2bf(v);
    }
}

// MFMA GEMM layer 1: h1b[NN,128] bf16 + es1/ed1[NN,4] fp32, from x fp32.
__global__ __launch_bounds__(256) void k_mm1(const float* __restrict__ x,
                                             const u16* __restrict__ Wt1,
                                             u16* __restrict__ h1b,
                                             float* __restrict__ es1,
                                             float* __restrict__ ed1) {
    __shared__ __align__(16) s16 As[128 * 128];
    __shared__ __align__(16) s16 Bs[BN1 * 128];
    int t = threadIdx.x;
    int row0 = blockIdx.x * 128;
    #pragma unroll
    for (int i = 0; i < 16; ++i) {
        int c = t + i * 256;
        int r = c >> 5, k0 = (c & 31) * 4;
        float4 v = make_float4(0.f, 0.f, 0.f, 0.f);
        int row = row0 + r;
        if (row < NN) v = *(const float4*)&x[(size_t)row * 128 + k0];
        u16 pk[4] = {f2bf(v.x), f2bf(v.y), f2bf(v.z), f2bf(v.w)};
        int byte = (r * 256 + k0 * 2) ^ ((r & 7) << 4);
        *(uint2*)((char*)As + byte) = *(uint2*)pk;
    }
    #pragma unroll
    for (int i = 0; i < 9; ++i) {
        int c = t + i * 256;
        int n = c >> 4, k0 = (c & 15) * 8;
        uint4 v = *(const uint4*)&Wt1[n * 128 + k0];
        int byte = (n * 256 + k0 * 2) ^ ((n & 7) << 4);
        *(uint4*)((char*)Bs + byte) = v;
    }
    __syncthreads();
    int wave = t >> 6, lane = t & 63;
    int lr = lane & 15, lq = lane >> 4;
    int wrow = wave * 32;
    f32x4 acc[2][9];
    #pragma unroll
    for (int a = 0; a < 2; ++a)
        #pragma unroll
        for (int b = 0; b < 9; ++b) acc[a][b] = (f32x4){0.f, 0.f, 0.f, 0.f};
    #pragma unroll
    for (int ks = 0; ks < 4; ++ks) {
        int kb = ks * 32 + lq * 8;
        bf16x8 af[2];
        #pragma unroll
        for (int rb = 0; rb < 2; ++rb) {
            int r = wrow + rb * 16 + lr;
            int byte = (r * 256 + kb * 2) ^ ((r & 7) << 4);
            af[rb] = *(bf16x8*)((char*)As + byte);
        }
        #pragma unroll
        for (int cb = 0; cb < 9; ++cb) {
            int n = cb * 16 + lr;
            int byte = (n * 256 + kb * 2) ^ ((n & 7) << 4);
            bf16x8 bfr = *(bf16x8*)((char*)Bs + byte);
            acc[0][cb] = __builtin_amdgcn_mfma_f32_16x16x32_bf16(af[0], bfr, acc[0][cb], 0, 0, 0);
            acc[1][cb] = __builtin_amdgcn_mfma_f32_16x16x32_bf16(af[1], bfr, acc[1][cb], 0, 0, 0);
        }
    }
    #pragma unroll
    for (int rb = 0; rb < 2; ++rb) {
        #pragma unroll
        for (int cb = 0; cb < 9; ++cb) {
            #pragma unroll
            for (int r = 0; r < 4; ++r) {
                int row = row0 + wrow + rb * 16 + lq * 4 + r;
                int col = cb * 16 + lr;
                if (row < NN) {
                    float v = acc[rb][cb][r];
                    if (col < 128) h1b[(size_t)row * 128 + col] = f2bf(v);
                    else if (col < 132) es1[row * 4 + (col - 128)] = v;
                    else if (col < 136) ed1[row * 4 + (col - 132)] = v;
                }
            }
        }
    }
}

// MFMA GEMM layer 2: h2[NN,40] fp32 + es2/ed2[NN] fp32, from hbnb bf16.
__global__ __launch_bounds__(256) void k_mm2(const u16* __restrict__ hbnb,
                                             const u16* __restrict__ Wt2,
                                             float* __restrict__ h2,
                                             float* __restrict__ es2,
                                             float* __restrict__ ed2) {
    __shared__ __align__(16) s16 As[128 * 128];
    __shared__ __align__(16) s16 Bs[BN2 * 128];
    int t = threadIdx.x;
    int row0 = blockIdx.x * 128;
    #pragma unroll
    for (int i = 0; i < 8; ++i) {
        int c = t + i * 256;
        int r = c >> 4, k0 = (c & 15) * 8;
        uint4 v = make_uint4(0, 0, 0, 0);
        int row = row0 + r;
        if (row < NN) v = *(const uint4*)&hbnb[(size_t)row * 128 + k0];
        int byte = (r * 256 + k0 * 2) ^ ((r & 7) << 4);
        *(uint4*)((char*)As + byte) = v;
    }
    #pragma unroll
    for (int i = 0; i < 3; ++i) {
        int c = t + i * 256;
        int n = c >> 4, k0 = (c & 15) * 8;
        uint4 v = *(const uint4*)&Wt2[n * 128 + k0];
        int byte = (n * 256 + k0 * 2) ^ ((n & 7) << 4);
        *(uint4*)((char*)Bs + byte) = v;
    }
    __syncthreads();
    int wave = t >> 6, lane = t & 63;
    int lr = lane & 15, lq = lane >> 4;
    int wrow = wave * 32;
    f32x4 acc[2][3];
    #pragma unroll
    for (int a = 0; a < 2; ++a)
        #pragma unroll
        for (int b = 0; b < 3; ++b) acc[a][b] = (f32x4){0.f, 0.f, 0.f, 0.f};
    #pragma unroll
    for (int ks = 0; ks < 4; ++ks) {
        int kb = ks * 32 + lq * 8;
        bf16x8 af[2];
        #pragma unroll
        for (int rb = 0; rb < 2; ++rb) {
            int r = wrow + rb * 16 + lr;
            int byte = (r * 256 + kb * 2) ^ ((r & 7) << 4);
            af[rb] = *(bf16x8*)((char*)As + byte);
        }
        #pragma unroll
        for (int cb = 0; cb < 3; ++cb) {
            int n = cb * 16 + lr;
            int byte = (n * 256 + kb * 2) ^ ((n & 7) << 4);
            bf16x8 bfr = *(bf16x8*)((char*)Bs + byte);
            acc[0][cb] = __builtin_amdgcn_mfma_f32_16x16x32_bf16(af[0], bfr, acc[0][cb], 0, 0, 0);
            acc[1][cb] = __builtin_amdgcn_mfma_f32_16x16x32_bf16(af[1], bfr, acc[1][cb], 0, 0, 0);
        }
    }
    #pragma unroll
    for (int rb = 0; rb < 2; ++rb) {
        #pragma unroll
        for (int cb = 0; cb < 3; ++cb) {
            #pragma unroll
            for (int r = 0; r < 4; ++r) {
                int row = row0 + wrow + rb * 16 + lq * 4 + r;
                int col = cb * 16 + lr;
                if (row < NN) {
                    float v = acc[rb][cb][r];
                    if (col < 40) h2[(size_t)row * 40 + col] = v;
                    else if (col == 40) es2[row] = v;
                    else if (col == 41) ed2[row] = v;
                }
            }
        }
    }
}

// layer-1 aggregation (plain-exp softmax, batched gather) + bias + BN + ELU -> bf16
__global__ __launch_bounds__(256) void k_agg1(
        const u16* __restrict__ h1b, const float* __restrict__ es,
        const float* __restrict__ ed, const int* __restrict__ offsets,
        const int* __restrict__ ssrc, const float* __restrict__ b1,
        const float* __restrict__ gamma, const float* __restrict__ beta,
        const float* __restrict__ mean, const float* __restrict__ var,
        u16* __restrict__ hbnb) {
    int node = blockIdx.x * 4 + (threadIdx.x >> 6);
    if (node >= NN) return;
    int l = threadIdx.x & 63;
    int head = l >> 4;
    int p0 = offsets[node], p1 = offsets[node + 1];
    float edv = ed[node * 4 + head];
    float s = 0.f, acc0 = 0.f, acc1 = 0.f;
    for (int base = p0; base < p1; base += 64) {
        int cnt = min(64, p1 - base);
        int myidx = (l < cnt) ? ssrc[base + l] : 0;
        int j = 0;
        for (; j + 4 <= cnt; j += 4) {
            int s0 = __shfl(myidx, j);
            int s1 = __shfl(myidx, j + 1);
            int s2 = __shfl(myidx, j + 2);
            int s3 = __shfl(myidx, j + 3);
            u32 w0 = *(const u32*)&h1b[(size_t)s0 * 128 + 2 * l];
            u32 w1 = *(const u32*)&h1b[(size_t)s1 * 128 + 2 * l];
            u32 w2 = *(const u32*)&h1b[(size_t)s2 * 128 + 2 * l];
            u32 w3 = *(const u32*)&h1b[(size_t)s3 * 128 + 2 * l];
            float e0 = es[s0 * 4 + head] + edv;
            float e1 = es[s1 * 4 + head] + edv;
            float e2 = es[s2 * 4 + head] + edv;
            float e3 = es[s3 * 4 + head] + edv;
            e0 = e0 > 0.f ? e0 : LEAKY * e0;  float x0 = __expf(e0);
            e1 = e1 > 0.f ? e1 : LEAKY * e1;  float x1 = __expf(e1);
            e2 = e2 > 0.f ? e2 : LEAKY * e2;  float x2 = __expf(e2);
            e3 = e3 > 0.f ? e3 : LEAKY * e3;  float x3 = __expf(e3);
            s += (x0 + x1) + (x2 + x3);
            acc0 = fmaf(x0, bf2f(w0 & 0xffffu), acc0);
            acc1 = fmaf(x0, bf2f(w0 >> 16), acc1);
            acc0 = fmaf(x1, bf2f(w1 & 0xffffu), acc0);
            acc1 = fmaf(x1, bf2f(w1 >> 16), acc1);
            acc0 = fmaf(x2, bf2f(w2 & 0xffffu), acc0);
            acc1 = fmaf(x2, bf2f(w2 >> 16), acc1);
            acc0 = fmaf(x3, bf2f(w3 & 0xffffu), acc0);
            acc1 = fmaf(x3, bf2f(w3 >> 16), acc1);
        }
        for (; j < cnt; ++j) {
            int s0 = __shfl(myidx, j);
            u32 w0 = *(const u32*)&h1b[(size_t)s0 * 128 + 2 * l];
            float e0 = es[s0 * 4 + head] + edv;
            e0 = e0 > 0.f ? e0 : LEAKY * e0;
            float x0 = __expf(e0);
            s += x0;
            acc0 = fmaf(x0, bf2f(w0 & 0xffffu), acc0);
            acc1 = fmaf(x0, bf2f(w0 >> 16), acc1);
        }
    }
    float inv = 1.f / s;
    int i0 = 2 * l, i1 = 2 * l + 1;
    float o0 = acc0 * inv + b1[i0];
    float o1 = acc1 * inv + b1[i1];
    o0 = (o0 - mean[i0]) * rsqrtf(var[i0] + BN_EPS) * gamma[i0] + beta[i0];
    o1 = (o1 - mean[i1]) * rsqrtf(var[i1] + BN_EPS) * gamma[i1] + beta[i1];
    o0 = o0 > 0.f ? o0 : __expf(o0) - 1.f;
    o1 = o1 > 0.f ? o1 : __expf(o1) - 1.f;
    u32 pk = (u32)f2bf(o0) | ((u32)f2bf(o1) << 16);
    *(u32*)&hbnb[(size_t)node * 128 + 2 * l] = pk;
}

// layer-2 aggregation (plain-exp softmax, batched gather) + bias + log_softmax
__global__ __launch_bounds__(256) void k_agg2(
        const float* __restrict__ h2, const float* __restrict__ es,
        const float* __restrict__ ed, const int* __restrict__ offsets,
        const int* __restrict__ ssrc, const float* __restrict__ b2,
        float* __restrict__ out) {
    int node = blockIdx.x * 4 + (threadIdx.x >> 6);
    if (node >= NN) return;
    int l = threadIdx.x & 63;
    int p0 = offsets[node], p1 = offsets[node + 1];
    float edv = ed[node];
    float s = 0.f, acc = 0.f;
    bool pay = (l < 40);
    for (int base = p0; base < p1; base += 64) {
        int cnt = min(64, p1 - base);
        int myidx = (l < cnt) ? ssrc[base + l] : 0;
        int j = 0;
        for (; j + 4 <= cnt; j += 4) {
            int s0 = __shfl(myidx, j);
            int s1 = __shfl(myidx, j + 1);
            int s2 = __shfl(myidx, j + 2);
            int s3 = __shfl(myidx, j + 3);
            float h0 = pay ? h2[(size_t)s0 * 40 + l] : 0.f;
            float h1v = pay ? h2[(size_t)s1 * 40 + l] : 0.f;
            float h2v = pay ? h2[(size_t)s2 * 40 + l] : 0.f;
            float h3 = pay ? h2[(size_t)s3 * 40 + l] : 0.f;
            float e0 = es[s0] + edv;
            float e1 = es[s1] + edv;
            float e2 = es[s2] + edv;
            float e3 = es[s3] + edv;
            e0 = e0 > 0.f ? e0 : LEAKY * e0;  float x0 = __expf(e0);
            e1 = e1 > 0.f ? e1 : LEAKY * e1;  float x1 = __expf(e1);
            e2 = e2 > 0.f ? e2 : LEAKY * e2;  float x2 = __expf(e2);
            e3 = e3 > 0.f ? e3 : LEAKY * e3;  float x3 = __expf(e3);
            s += (x0 + x1) + (x2 + x3);
            acc = fmaf(x0, h0, acc);
            acc = fmaf(x1, h1v, acc);
            acc = fmaf(x2, h2v, acc);
            acc = fmaf(x3, h3, acc);
        }
        for (; j < cnt; ++j) {
            int s0 = __shfl(myidx, j);
            float h0 = pay ? h2[(size_t)s0 * 40 + l] : 0.f;
            float e0 = es[s0] + edv;
            e0 = e0 > 0.f ? e0 : LEAKY * e0;
            float x0 = __expf(e0);
            s += x0;
            acc = fmaf(x0, h0, acc);
        }
    }
    float v = acc / s + (pay ? b2[l] : 0.f);
    float mv = pay ? v : -1e30f;
    #pragma unroll
    for (int off = 1; off < 64; off <<= 1) mv = fmaxf(mv, __shfl_xor(mv, off));
    float ex = pay ? __expf(v - mv) : 0.f;
    #pragma unroll
    for (int off = 1; off < 64; off <<= 1) ex += __shfl_xor(ex, off);
    if (pay) out[(size_t)node * 40 + l] = v - mv - __logf(ex);
}

extern "C" void kernel_launch(void* const* d_in, const int* in_sizes, int n_in,
                              void* d_out, int out_size, void* d_ws, size_t ws_size,
                              hipStream_t stream) {
    const float* x   = (const float*)d_in[0];
    const int*   ei  = (const int*)d_in[1];
    const float* W1  = (const float*)d_in[2];
    const float* a1s = (const float*)d_in[3];
    const float* a1d = (const float*)d_in[4];
    const float* b1  = (const float*)d_in[5];
    const float* bng = (const float*)d_in[6];
    const float* bnb = (const float*)d_in[7];
    const float* bnm = (const float*)d_in[8];
    const float* bnv = (const float*)d_in[9];
    const float* W2  = (const float*)d_in[10];
    const float* a2s = (const float*)d_in[11];
    const float* a2d = (const float*)d_in[12];
    const float* b2  = (const float*)d_in[13];
    float* out = (float*)d_out;

    char* ws = (char*)d_ws;
    size_t off = 0;
    auto alloc = [&](size_t bytes) -> void* {
        void* p = ws + off;
        off = (off + bytes + 255) & ~(size_t)255;
        return p;
    };
    int*   cntb     = (int*)alloc((size_t)NB * NBB * 4);
    int*   excl     = (int*)alloc((size_t)NB * NBB * 4);
    int*   bsums    = (int*)alloc((size_t)NBB * 4);
    int*   offsets  = (int*)alloc((size_t)(NN + 1) * 4);
    u32*   packed   = (u32*)alloc((size_t)ETOT * 4);
    int*   ssrc     = (int*)alloc((size_t)ETOT * 4);
    u16*   Wt1      = (u16*)alloc((size_t)BN1 * 128 * 2);
    u16*   Wt2      = (u16*)alloc((size_t)BN2 * 128 * 2);
    u16*   h1b      = (u16*)alloc((size_t)NN * 128 * 2);
    float* es1      = (float*)alloc((size_t)NN * 4 * 4);
    float* ed1      = (float*)alloc((size_t)NN * 4 * 4);
    u16*   hbnb     = (u16*)alloc((size_t)NN * 128 * 2);
    float* h2       = (float*)alloc((size_t)NN * 40 * 4);
    float* es2      = (float*)alloc((size_t)NN * 4);
    float* ed2      = (float*)alloc((size_t)NN * 4);

    const int nscan = NB * NBB;  // 32768
    k_prep<<<80, 256, 0, stream>>>(W1, a1s, a1d, W2, a2s, a2d, Wt1, Wt2);
    k_binA<<<NBB, 256, 0, stream>>>(ei, cntb);
    k_scanA<<<nscan / 256, 256, 0, stream>>>(cntb, excl, bsums, nscan);
    k_scanB<<<1, 256, 0, stream>>>(bsums, NBB);
    k_scanC<<<nscan / 256, 256, 0, stream>>>(excl, bsums, nscan);
    k_binB<<<NBB, 256, 0, stream>>>(ei, excl, packed);
    k_binC<<<NB, 256, 0, stream>>>(packed, excl, offsets, ssrc);
    k_mm1<<<(NN + 127) / 128, 256, 0, stream>>>(x, Wt1, h1b, es1, ed1);
    k_agg1<<<(NN + 3) / 4, 256, 0, stream>>>(h1b, es1, ed1, offsets, ssrc,
                                             b1, bng, bnb, bnm, bnv, hbnb);
    k_mm2<<<(NN + 127) / 128, 256, 0, stream>>>(hbnb, Wt2, h2, es2, ed2);
    k_agg2<<<(NN + 3) / 4, 256, 0, stream>>>(h2, es2, ed2, offsets, ssrc, b2, out);
}